// Round 1
// baseline (1139.656 us; speedup 1.0000x reference)
//
#include <hip/hip_runtime.h>
#include <math.h>

// ---------------------------------------------------------------------------
// 2-layer GraphSAGE (mean aggr) + dot-product link predictor, fp32.
// Pipeline: cnt -> scatter(x) -> layer1(relu) -> scatter(h) -> layer2 -> link
// ---------------------------------------------------------------------------

#define F_IN 128
#define F_HID 128
#define F_OUT 64

// in-degree count: cnt[dst[e]] += 1
__global__ void count_kernel(const int* __restrict__ dst,
                             float* __restrict__ cnt, int E) {
    int e = blockIdx.x * blockDim.x + threadIdx.x;
    if (e < E) atomicAdd(&cnt[dst[e]], 1.0f);
}

// agg[dst[e]][f] += feat[src[e]][f], F = 128 (one thread per (edge, feature))
__global__ void scatter128_kernel(const float* __restrict__ feat,
                                  const int* __restrict__ src,
                                  const int* __restrict__ dst,
                                  float* __restrict__ agg, int E) {
    long long tid = (long long)blockIdx.x * blockDim.x + threadIdx.x;
    long long total = (long long)E * F_IN;
    if (tid >= total) return;
    int e = (int)(tid >> 7);     // / 128
    int f = (int)(tid & 127);    // % 128
    int s = src[e];
    int d = dst[e];
    atomicAdd(&agg[(long long)d * F_IN + f], feat[(long long)s * F_IN + f]);
}

// h[i][o] = relu( sum_f (agg[i][f]/max(cnt,1)) * W1l[f][o] + b1[o]
//                 + sum_f x[i][f] * W1r[f][o] )          o in [0,128)
__global__ void layer1_kernel(const float* __restrict__ x,
                              const float* __restrict__ agg,
                              const float* __restrict__ cnt,
                              const float* __restrict__ W1l,
                              const float* __restrict__ b1,
                              const float* __restrict__ W1r,
                              float* __restrict__ h, int N) {
    __shared__ float xs[F_IN];
    __shared__ float as[F_IN];
    int i = blockIdx.x;
    int o = threadIdx.x;            // 128 threads
    if (i >= N) return;
    float inv = 1.0f / fmaxf(cnt[i], 1.0f);
    xs[o] = x[(long long)i * F_IN + o];
    as[o] = agg[(long long)i * F_IN + o] * inv;
    __syncthreads();
    float acc = b1[o];
    #pragma unroll 8
    for (int f = 0; f < F_IN; ++f) {
        acc += as[f] * W1l[f * F_HID + o] + xs[f] * W1r[f * F_HID + o];
    }
    h[(long long)i * F_HID + o] = fmaxf(acc, 0.0f);
}

// z[i][o] = sum_f (agg[i][f]/max(cnt,1)) * W2l[f][o] + b2[o]
//           + sum_f h[i][f] * W2r[f][o]               o in [0,64)
__global__ void layer2_kernel(const float* __restrict__ h,
                              const float* __restrict__ agg,
                              const float* __restrict__ cnt,
                              const float* __restrict__ W2l,
                              const float* __restrict__ b2,
                              const float* __restrict__ W2r,
                              float* __restrict__ z, int N) {
    __shared__ float hs[F_HID];
    __shared__ float as[F_HID];
    int i = blockIdx.x;
    int o = threadIdx.x;            // 64 threads
    if (i >= N) return;
    float inv = 1.0f / fmaxf(cnt[i], 1.0f);
    hs[o]      = h[(long long)i * F_HID + o];
    hs[o + 64] = h[(long long)i * F_HID + o + 64];
    as[o]      = agg[(long long)i * F_HID + o] * inv;
    as[o + 64] = agg[(long long)i * F_HID + o + 64] * inv;
    __syncthreads();
    float acc = b2[o];
    #pragma unroll 8
    for (int f = 0; f < F_HID; ++f) {
        acc += as[f] * W2l[f * F_OUT + o] + hs[f] * W2r[f * F_OUT + o];
    }
    z[(long long)i * F_OUT + o] = acc;
}

// out[p] = sigmoid( sum_k z[ps][k]*Wlin[k] + z[pd][k]*Wlin[64+k] + blin )
// one 64-lane wave per pair; 4 pairs per 256-thread block
__global__ void link_kernel(const float* __restrict__ z,
                            const int* __restrict__ ps,
                            const int* __restrict__ pd,
                            const float* __restrict__ Wlin,
                            const float* __restrict__ blin,
                            float* __restrict__ out, int P) {
    int p = blockIdx.x * 4 + (threadIdx.x >> 6);
    int lane = threadIdx.x & 63;
    if (p >= P) return;
    int a = ps[p];
    int b = pd[p];
    float v = z[(long long)a * F_OUT + lane] * Wlin[lane]
            + z[(long long)b * F_OUT + lane] * Wlin[64 + lane];
    // wave-64 butterfly reduce
    #pragma unroll
    for (int off = 32; off > 0; off >>= 1) {
        v += __shfl_down(v, off, 64);
    }
    if (lane == 0) {
        float logit = v + blin[0];
        out[p] = 1.0f / (1.0f + expf(-logit));
    }
}

extern "C" void kernel_launch(void* const* d_in, const int* in_sizes, int n_in,
                              void* d_out, int out_size, void* d_ws, size_t ws_size,
                              hipStream_t stream) {
    const float* x          = (const float*)d_in[0];
    const int*   edge_index = (const int*)d_in[1];
    const int*   edge_pairs = (const int*)d_in[2];
    const float* W1l        = (const float*)d_in[3];
    const float* b1         = (const float*)d_in[4];
    const float* W1r        = (const float*)d_in[5];
    const float* W2l        = (const float*)d_in[6];
    const float* b2         = (const float*)d_in[7];
    const float* W2r        = (const float*)d_in[8];
    const float* Wlin       = (const float*)d_in[9];
    const float* blin       = (const float*)d_in[10];
    float* out = (float*)d_out;

    const int N = in_sizes[0] / F_IN;      // 50000
    const int E = in_sizes[1] / 2;         // 800000
    const int P = in_sizes[2] / 2;         // 200000

    const int* src = edge_index;
    const int* dst = edge_index + E;
    const int* ps  = edge_pairs;
    const int* pd  = edge_pairs + P;

    // workspace layout: agg[N*128] | h[N*128] | z[N*64] | cnt[N]
    float* agg = (float*)d_ws;
    float* h   = agg + (size_t)N * F_IN;
    float* z   = h   + (size_t)N * F_HID;
    float* cnt = z   + (size_t)N * F_OUT;

    // ---- layer 1 ----
    hipMemsetAsync(agg, 0, (size_t)N * F_IN * sizeof(float), stream);
    hipMemsetAsync(cnt, 0, (size_t)N * sizeof(float), stream);

    count_kernel<<<(E + 255) / 256, 256, 0, stream>>>(dst, cnt, E);

    long long tot = (long long)E * F_IN;
    int nblk = (int)((tot + 255) / 256);
    scatter128_kernel<<<nblk, 256, 0, stream>>>(x, src, dst, agg, E);

    layer1_kernel<<<N, F_HID, 0, stream>>>(x, agg, cnt, W1l, b1, W1r, h, N);

    // ---- layer 2 ----
    hipMemsetAsync(agg, 0, (size_t)N * F_HID * sizeof(float), stream);
    scatter128_kernel<<<nblk, 256, 0, stream>>>(h, src, dst, agg, E);

    layer2_kernel<<<N, F_OUT, 0, stream>>>(h, agg, cnt, W2l, b2, W2r, z, N);

    // ---- link prediction ----
    link_kernel<<<(P + 3) / 4, 256, 0, stream>>>(z, ps, pd, Wlin, blin, out, P);
}

// Round 2
// 558.537 us; speedup vs baseline: 2.0404x; 2.0404x over previous
//
#include <hip/hip_runtime.h>
#include <math.h>

// ---------------------------------------------------------------------------
// 2-layer GraphSAGE (mean aggr) + link predictor, fp32. CSR-gather version.
//
// Pipeline:
//   hist(deg) -> scan(rowptr,cursor) -> fill(esrc)          [CSR build]
//   agg1: mean_x = mean_{j in N(i)} x_j                      (gather, no atomics)
//   GEMM1: h = relu([mean_x | x] @ [W1l; W1r] + b1)          (tiled LDS GEMM)
//   GEMM2: [t|u] = h @ [W2l | W2r]                           (tiled LDS GEMM)
//   agg2:  z = mean_{j}(t_j) + u_i + b2                      (gather + epilogue)
//   link:  sigmoid(dot)
//
// ws layout: A[N*128] (mean_x -> tu) | B[N*128] (h -> z) | deg | rowptr | cursor | esrc
// ---------------------------------------------------------------------------

#define F_IN 128
#define F_OUT 64

// ---- CSR build -------------------------------------------------------------

__global__ void hist_kernel(const int* __restrict__ dst, int* __restrict__ deg, int E) {
    int e = blockIdx.x * blockDim.x + threadIdx.x;
    if (e < E) atomicAdd(&deg[dst[e]], 1);
}

// single-block exclusive scan (1024 threads), also writes cursor copy
__global__ void scan_kernel(const int* __restrict__ deg, int* __restrict__ rowptr,
                            int* __restrict__ cursor, int N) {
    __shared__ int part[1024];
    int t = threadIdx.x;
    int chunk = (N + 1023) / 1024;
    int lo = t * chunk;
    int hi = lo + chunk; if (hi > N) hi = N;
    int s = 0;
    for (int i = lo; i < hi; ++i) s += deg[i];
    part[t] = s;
    __syncthreads();
    for (int off = 1; off < 1024; off <<= 1) {
        int v = (t >= off) ? part[t - off] : 0;
        __syncthreads();
        part[t] += v;
        __syncthreads();
    }
    int run = (t == 0) ? 0 : part[t - 1];
    for (int i = lo; i < hi; ++i) {
        rowptr[i] = run;
        cursor[i] = run;
        run += deg[i];
    }
    if (t == 1023) rowptr[N] = part[1023];
}

__global__ void fill_kernel(const int* __restrict__ src, const int* __restrict__ dst,
                            int* __restrict__ cursor, int* __restrict__ esrc, int E) {
    int e = blockIdx.x * blockDim.x + threadIdx.x;
    if (e < E) {
        int pos = atomicAdd(&cursor[dst[e]], 1);
        esrc[pos] = src[e];
    }
}

// ---- aggregation (gather) --------------------------------------------------

// mean over 128 features: one wave per node, float2 per lane
__global__ void agg_mean_x_kernel(const float* __restrict__ x,
                                  const int* __restrict__ rowptr,
                                  const int* __restrict__ esrc,
                                  float* __restrict__ mean, int N) {
    int node = blockIdx.x * 4 + (threadIdx.x >> 6);
    int lane = threadIdx.x & 63;
    if (node >= N) return;
    int s0 = rowptr[node], s1 = rowptr[node + 1];
    float ax = 0.f, ay = 0.f;
    for (int k = s0; k < s1; ++k) {
        int s = esrc[k];
        float2 v = *(const float2*)(x + (size_t)s * 128 + lane * 2);
        ax += v.x; ay += v.y;
    }
    float inv = 1.0f / fmaxf((float)(s1 - s0), 1.0f);
    *(float2*)(mean + (size_t)node * 128 + lane * 2) = make_float2(ax * inv, ay * inv);
}

// mean over t (cols 0..63 of tu) + u (cols 64..127) + b2 -> z[N,64]
__global__ void agg_mean_t_kernel(const float* __restrict__ tu,
                                  const int* __restrict__ rowptr,
                                  const int* __restrict__ esrc,
                                  const float* __restrict__ b2,
                                  float* __restrict__ z, int N) {
    int node = blockIdx.x * 4 + (threadIdx.x >> 6);
    int lane = threadIdx.x & 63;
    if (node >= N) return;
    int s0 = rowptr[node], s1 = rowptr[node + 1];
    float acc = 0.f;
    for (int k = s0; k < s1; ++k) {
        int s = esrc[k];
        acc += tu[(size_t)s * 128 + lane];
    }
    float inv = 1.0f / fmaxf((float)(s1 - s0), 1.0f);
    z[(size_t)node * 64 + lane] = acc * inv + tu[(size_t)node * 128 + 64 + lane] + b2[lane];
}

// ---- tiled GEMMs -----------------------------------------------------------
// BM=32, BK=32, output width 128, 256 threads, each computes 4x4 micro-tile.

__global__ __launch_bounds__(256)
void gemm1_kernel(const float* __restrict__ mean, const float* __restrict__ x,
                  const float* __restrict__ W1l, const float* __restrict__ W1r,
                  const float* __restrict__ b1, float* __restrict__ h, int N) {
    __shared__ float sA[32][36];
    __shared__ float sB[32][128];
    int tid = threadIdx.x;
    int tx = tid & 31;
    int ty = tid >> 5;
    int row0 = blockIdx.x * 32;
    int lr = tid >> 3;            // 0..31 sA row
    int lk = (tid & 7) * 4;       // sA k offset
    int wc = (tid & 31) * 4;      // sB col
    int wr = tid >> 5;            // sB base row
    float acc[4][4] = {};
    for (int kb = 0; kb < 8; ++kb) {
        const float* srcp = (kb < 4) ? mean : x;
        int koff = (kb & 3) * 32;
        int gi = row0 + lr;
        float4 av = make_float4(0.f, 0.f, 0.f, 0.f);
        if (gi < N) av = *(const float4*)(srcp + (size_t)gi * 128 + koff + lk);
        *(float4*)&sA[lr][lk] = av;
        const float* W = (kb < 4) ? W1l : W1r;
        #pragma unroll
        for (int i = 0; i < 4; ++i) {
            int r = wr + 8 * i;
            *(float4*)&sB[r][wc] = *(const float4*)(W + (size_t)(koff + r) * 128 + wc);
        }
        __syncthreads();
        #pragma unroll
        for (int kk = 0; kk < 32; ++kk) {
            float a[4], b[4];
            #pragma unroll
            for (int i = 0; i < 4; ++i) a[i] = sA[ty * 4 + i][kk];
            #pragma unroll
            for (int c = 0; c < 4; ++c) b[c] = sB[kk][tx + 32 * c];
            #pragma unroll
            for (int i = 0; i < 4; ++i)
                #pragma unroll
                for (int c = 0; c < 4; ++c)
                    acc[i][c] += a[i] * b[c];
        }
        __syncthreads();
    }
    #pragma unroll
    for (int i = 0; i < 4; ++i) {
        int gi = row0 + ty * 4 + i;
        if (gi >= N) continue;
        #pragma unroll
        for (int c = 0; c < 4; ++c) {
            int col = tx + 32 * c;
            h[(size_t)gi * 128 + col] = fmaxf(acc[i][c] + b1[col], 0.f);
        }
    }
}

// tu = h @ [W2l | W2r]  (K=128; W2l,W2r are [128,64])
__global__ __launch_bounds__(256)
void gemm2_kernel(const float* __restrict__ h,
                  const float* __restrict__ W2l, const float* __restrict__ W2r,
                  float* __restrict__ tu, int N) {
    __shared__ float sA[32][36];
    __shared__ float sB[32][128];
    int tid = threadIdx.x;
    int tx = tid & 31;
    int ty = tid >> 5;
    int row0 = blockIdx.x * 32;
    int lr = tid >> 3;
    int lk = (tid & 7) * 4;
    int wc = (tid & 31) * 4;
    int wr = tid >> 5;
    float acc[4][4] = {};
    for (int kb = 0; kb < 4; ++kb) {
        int koff = kb * 32;
        int gi = row0 + lr;
        float4 av = make_float4(0.f, 0.f, 0.f, 0.f);
        if (gi < N) av = *(const float4*)(h + (size_t)gi * 128 + koff + lk);
        *(float4*)&sA[lr][lk] = av;
        #pragma unroll
        for (int i = 0; i < 4; ++i) {
            int r = wr + 8 * i;
            int k = koff + r;
            float4 wv;
            if (wc < 64) wv = *(const float4*)(W2l + (size_t)k * 64 + wc);
            else         wv = *(const float4*)(W2r + (size_t)k * 64 + (wc - 64));
            *(float4*)&sB[r][wc] = wv;
        }
        __syncthreads();
        #pragma unroll
        for (int kk = 0; kk < 32; ++kk) {
            float a[4], b[4];
            #pragma unroll
            for (int i = 0; i < 4; ++i) a[i] = sA[ty * 4 + i][kk];
            #pragma unroll
            for (int c = 0; c < 4; ++c) b[c] = sB[kk][tx + 32 * c];
            #pragma unroll
            for (int i = 0; i < 4; ++i)
                #pragma unroll
                for (int c = 0; c < 4; ++c)
                    acc[i][c] += a[i] * b[c];
        }
        __syncthreads();
    }
    #pragma unroll
    for (int i = 0; i < 4; ++i) {
        int gi = row0 + ty * 4 + i;
        if (gi >= N) continue;
        #pragma unroll
        for (int c = 0; c < 4; ++c) {
            int col = tx + 32 * c;
            tu[(size_t)gi * 128 + col] = acc[i][c];
        }
    }
}

// ---- link prediction -------------------------------------------------------

__global__ void link_kernel(const float* __restrict__ z,
                            const int* __restrict__ ps,
                            const int* __restrict__ pd,
                            const float* __restrict__ Wlin,
                            const float* __restrict__ blin,
                            float* __restrict__ out, int P) {
    int p = blockIdx.x * 4 + (threadIdx.x >> 6);
    int lane = threadIdx.x & 63;
    if (p >= P) return;
    int a = ps[p];
    int b = pd[p];
    float v = z[(size_t)a * F_OUT + lane] * Wlin[lane]
            + z[(size_t)b * F_OUT + lane] * Wlin[64 + lane];
    #pragma unroll
    for (int off = 32; off > 0; off >>= 1) v += __shfl_down(v, off, 64);
    if (lane == 0) out[p] = 1.0f / (1.0f + expf(-(v + blin[0])));
}

// ---------------------------------------------------------------------------

extern "C" void kernel_launch(void* const* d_in, const int* in_sizes, int n_in,
                              void* d_out, int out_size, void* d_ws, size_t ws_size,
                              hipStream_t stream) {
    const float* x          = (const float*)d_in[0];
    const int*   edge_index = (const int*)d_in[1];
    const int*   edge_pairs = (const int*)d_in[2];
    const float* W1l        = (const float*)d_in[3];
    const float* b1         = (const float*)d_in[4];
    const float* W1r        = (const float*)d_in[5];
    const float* W2l        = (const float*)d_in[6];
    const float* b2         = (const float*)d_in[7];
    const float* W2r        = (const float*)d_in[8];
    const float* Wlin       = (const float*)d_in[9];
    const float* blin       = (const float*)d_in[10];
    float* out = (float*)d_out;

    const int N = in_sizes[0] / F_IN;      // 50000
    const int E = in_sizes[1] / 2;         // 800000
    const int P = in_sizes[2] / 2;         // 200000

    const int* src = edge_index;
    const int* dst = edge_index + E;
    const int* ps  = edge_pairs;
    const int* pd  = edge_pairs + P;

    float* A = (float*)d_ws;               // mean_x, then tu
    float* B = A + (size_t)N * 128;        // h, then z (first N*64)
    int* deg    = (int*)(B + (size_t)N * 128);
    int* rowptr = deg + N;
    int* cursor = rowptr + N + 1;
    int* esrc   = cursor + N;

    // CSR build
    hipMemsetAsync(deg, 0, (size_t)N * sizeof(int), stream);
    hist_kernel<<<(E + 255) / 256, 256, 0, stream>>>(dst, deg, E);
    scan_kernel<<<1, 1024, 0, stream>>>(deg, rowptr, cursor, N);
    fill_kernel<<<(E + 255) / 256, 256, 0, stream>>>(src, dst, cursor, esrc, E);

    // layer 1
    agg_mean_x_kernel<<<(N + 3) / 4, 256, 0, stream>>>(x, rowptr, esrc, A, N);
    gemm1_kernel<<<(N + 31) / 32, 256, 0, stream>>>(A, x, W1l, W1r, b1, B, N);

    // layer 2 (transform first, aggregate 64-dim t)
    gemm2_kernel<<<(N + 31) / 32, 256, 0, stream>>>(B, W2l, W2r, A, N);
    agg_mean_t_kernel<<<(N + 3) / 4, 256, 0, stream>>>(A, rowptr, esrc, b2, B, N);

    // link prediction (z lives in B)
    link_kernel<<<(P + 3) / 4, 256, 0, stream>>>(B, ps, pd, Wlin, blin, out, P);
}

// Round 3
// 465.005 us; speedup vs baseline: 2.4508x; 1.2011x over previous
//
#include <hip/hip_runtime.h>
#include <math.h>

// ---------------------------------------------------------------------------
// 2-layer GraphSAGE (mean aggr) + link predictor, fp32. CSR-gather version.
//
// Pipeline:
//   hist(deg) -> 3-phase scan(rowptr,cursor) -> fill(esrc)   [CSR build]
//   agg1: mean_x = mean_{j in N(i)} x_j                      (gather, no atomics)
//   GEMM1: h = relu([mean_x | x] @ [W1l; W1r] + b1)          (tiled LDS GEMM)
//   GEMM2: [t|u] = h @ [W2l | W2r]                           (tiled LDS GEMM)
//   agg2:  z = mean_{j}(t_j) + u_i + b2                      (gather + epilogue)
//   link:  sigmoid(dot)
//
// ws: A[N*128] | B[N*128] | deg | rowptr | cursor | esrc | partials
// ---------------------------------------------------------------------------

#define F_IN 128
#define F_OUT 64

// ---- CSR build -------------------------------------------------------------

__global__ void hist_kernel(const int* __restrict__ dst, int* __restrict__ deg, int E) {
    int e = blockIdx.x * blockDim.x + threadIdx.x;
    if (e < E) atomicAdd(&deg[dst[e]], 1);
}

// phase B: per-block sum of 256 deg entries
__global__ void partial_sum_kernel(const int* __restrict__ deg,
                                   int* __restrict__ partials, int N) {
    __shared__ int ws[4];
    int i = blockIdx.x * 256 + threadIdx.x;
    int t = threadIdx.x;
    int v = (i < N) ? deg[i] : 0;
    #pragma unroll
    for (int off = 32; off > 0; off >>= 1) v += __shfl_down(v, off, 64);
    if ((t & 63) == 0) ws[t >> 6] = v;
    __syncthreads();
    if (t == 0) partials[blockIdx.x] = ws[0] + ws[1] + ws[2] + ws[3];
}

// phase C: single small block, exclusive scan of partials in place (nb <= 256)
__global__ void scan_partials_kernel(int* __restrict__ partials, int nb) {
    __shared__ int buf[256];
    int t = threadIdx.x;
    int v = (t < nb) ? partials[t] : 0;
    buf[t] = v;
    __syncthreads();
    for (int off = 1; off < 256; off <<= 1) {
        int u = (t >= off) ? buf[t - off] : 0;
        __syncthreads();
        buf[t] += u;
        __syncthreads();
    }
    if (t < nb) partials[t] = (t == 0) ? 0 : buf[t - 1];
}

// phase D: per-block scan + block offset -> rowptr & cursor
__global__ void scan_final_kernel(const int* __restrict__ deg,
                                  const int* __restrict__ blockoff,
                                  int* __restrict__ rowptr,
                                  int* __restrict__ cursor, int N) {
    __shared__ int buf[256];
    int i = blockIdx.x * 256 + threadIdx.x;
    int t = threadIdx.x;
    int v = (i < N) ? deg[i] : 0;
    buf[t] = v;
    __syncthreads();
    for (int off = 1; off < 256; off <<= 1) {
        int u = (t >= off) ? buf[t - off] : 0;
        __syncthreads();
        buf[t] += u;
        __syncthreads();
    }
    int excl = blockoff[blockIdx.x] + ((t == 0) ? 0 : buf[t - 1]);
    if (i < N) {
        rowptr[i] = excl;
        cursor[i] = excl;
        if (i == N - 1) rowptr[N] = excl + v;
    }
}

__global__ void fill_kernel(const int* __restrict__ src, const int* __restrict__ dst,
                            int* __restrict__ cursor, int* __restrict__ esrc, int E) {
    int e = blockIdx.x * blockDim.x + threadIdx.x;
    if (e < E) {
        int pos = atomicAdd(&cursor[dst[e]], 1);
        esrc[pos] = src[e];
    }
}

// ---- aggregation (gather) --------------------------------------------------

// mean over 128 features: one wave per node, float2 per lane
__global__ void agg_mean_x_kernel(const float* __restrict__ x,
                                  const int* __restrict__ rowptr,
                                  const int* __restrict__ esrc,
                                  float* __restrict__ mean, int N) {
    int node = blockIdx.x * 4 + (threadIdx.x >> 6);
    int lane = threadIdx.x & 63;
    if (node >= N) return;
    int s0 = rowptr[node], s1 = rowptr[node + 1];
    float ax = 0.f, ay = 0.f;
    for (int k = s0; k < s1; ++k) {
        int s = esrc[k];
        float2 v = *(const float2*)(x + (size_t)s * 128 + lane * 2);
        ax += v.x; ay += v.y;
    }
    float inv = 1.0f / fmaxf((float)(s1 - s0), 1.0f);
    *(float2*)(mean + (size_t)node * 128 + lane * 2) = make_float2(ax * inv, ay * inv);
}

// mean over t (cols 0..63 of tu) + u (cols 64..127) + b2 -> z[N,64]
__global__ void agg_mean_t_kernel(const float* __restrict__ tu,
                                  const int* __restrict__ rowptr,
                                  const int* __restrict__ esrc,
                                  const float* __restrict__ b2,
                                  float* __restrict__ z, int N) {
    int node = blockIdx.x * 4 + (threadIdx.x >> 6);
    int lane = threadIdx.x & 63;
    if (node >= N) return;
    int s0 = rowptr[node], s1 = rowptr[node + 1];
    float acc = 0.f;
    for (int k = s0; k < s1; ++k) {
        int s = esrc[k];
        acc += tu[(size_t)s * 128 + lane];
    }
    float inv = 1.0f / fmaxf((float)(s1 - s0), 1.0f);
    z[(size_t)node * 64 + lane] = acc * inv + tu[(size_t)node * 128 + 64 + lane] + b2[lane];
}

// ---- tiled GEMMs -----------------------------------------------------------
// BM=32, BK=32, output width 128, 256 threads, each computes 4x4 micro-tile.

__global__ __launch_bounds__(256)
void gemm1_kernel(const float* __restrict__ mean, const float* __restrict__ x,
                  const float* __restrict__ W1l, const float* __restrict__ W1r,
                  const float* __restrict__ b1, float* __restrict__ h, int N) {
    __shared__ float sA[32][36];
    __shared__ float sB[32][128];
    int tid = threadIdx.x;
    int tx = tid & 31;
    int ty = tid >> 5;
    int row0 = blockIdx.x * 32;
    int lr = tid >> 3;            // 0..31 sA row
    int lk = (tid & 7) * 4;       // sA k offset
    int wc = (tid & 31) * 4;      // sB col
    int wr = tid >> 5;            // sB base row
    float acc[4][4] = {};
    for (int kb = 0; kb < 8; ++kb) {
        const float* srcp = (kb < 4) ? mean : x;
        int koff = (kb & 3) * 32;
        int gi = row0 + lr;
        float4 av = make_float4(0.f, 0.f, 0.f, 0.f);
        if (gi < N) av = *(const float4*)(srcp + (size_t)gi * 128 + koff + lk);
        *(float4*)&sA[lr][lk] = av;
        const float* W = (kb < 4) ? W1l : W1r;
        #pragma unroll
        for (int i = 0; i < 4; ++i) {
            int r = wr + 8 * i;
            *(float4*)&sB[r][wc] = *(const float4*)(W + (size_t)(koff + r) * 128 + wc);
        }
        __syncthreads();
        #pragma unroll
        for (int kk = 0; kk < 32; ++kk) {
            float a[4], b[4];
            #pragma unroll
            for (int i = 0; i < 4; ++i) a[i] = sA[ty * 4 + i][kk];
            #pragma unroll
            for (int c = 0; c < 4; ++c) b[c] = sB[kk][tx + 32 * c];
            #pragma unroll
            for (int i = 0; i < 4; ++i)
                #pragma unroll
                for (int c = 0; c < 4; ++c)
                    acc[i][c] += a[i] * b[c];
        }
        __syncthreads();
    }
    #pragma unroll
    for (int i = 0; i < 4; ++i) {
        int gi = row0 + ty * 4 + i;
        if (gi >= N) continue;
        #pragma unroll
        for (int c = 0; c < 4; ++c) {
            int col = tx + 32 * c;
            h[(size_t)gi * 128 + col] = fmaxf(acc[i][c] + b1[col], 0.f);
        }
    }
}

// tu = h @ [W2l | W2r]  (K=128; W2l,W2r are [128,64])
__global__ __launch_bounds__(256)
void gemm2_kernel(const float* __restrict__ h,
                  const float* __restrict__ W2l, const float* __restrict__ W2r,
                  float* __restrict__ tu, int N) {
    __shared__ float sA[32][36];
    __shared__ float sB[32][128];
    int tid = threadIdx.x;
    int tx = tid & 31;
    int ty = tid >> 5;
    int row0 = blockIdx.x * 32;
    int lr = tid >> 3;
    int lk = (tid & 7) * 4;
    int wc = (tid & 31) * 4;
    int wr = tid >> 5;
    float acc[4][4] = {};
    for (int kb = 0; kb < 4; ++kb) {
        int koff = kb * 32;
        int gi = row0 + lr;
        float4 av = make_float4(0.f, 0.f, 0.f, 0.f);
        if (gi < N) av = *(const float4*)(h + (size_t)gi * 128 + koff + lk);
        *(float4*)&sA[lr][lk] = av;
        #pragma unroll
        for (int i = 0; i < 4; ++i) {
            int r = wr + 8 * i;
            int k = koff + r;
            float4 wv;
            if (wc < 64) wv = *(const float4*)(W2l + (size_t)k * 64 + wc);
            else         wv = *(const float4*)(W2r + (size_t)k * 64 + (wc - 64));
            *(float4*)&sB[r][wc] = wv;
        }
        __syncthreads();
        #pragma unroll
        for (int kk = 0; kk < 32; ++kk) {
            float a[4], b[4];
            #pragma unroll
            for (int i = 0; i < 4; ++i) a[i] = sA[ty * 4 + i][kk];
            #pragma unroll
            for (int c = 0; c < 4; ++c) b[c] = sB[kk][tx + 32 * c];
            #pragma unroll
            for (int i = 0; i < 4; ++i)
                #pragma unroll
                for (int c = 0; c < 4; ++c)
                    acc[i][c] += a[i] * b[c];
        }
        __syncthreads();
    }
    #pragma unroll
    for (int i = 0; i < 4; ++i) {
        int gi = row0 + ty * 4 + i;
        if (gi >= N) continue;
        #pragma unroll
        for (int c = 0; c < 4; ++c) {
            int col = tx + 32 * c;
            tu[(size_t)gi * 128 + col] = acc[i][c];
        }
    }
}

// ---- link prediction -------------------------------------------------------

__global__ void link_kernel(const float* __restrict__ z,
                            const int* __restrict__ ps,
                            const int* __restrict__ pd,
                            const float* __restrict__ Wlin,
                            const float* __restrict__ blin,
                            float* __restrict__ out, int P) {
    int p = blockIdx.x * 4 + (threadIdx.x >> 6);
    int lane = threadIdx.x & 63;
    if (p >= P) return;
    int a = ps[p];
    int b = pd[p];
    float v = z[(size_t)a * F_OUT + lane] * Wlin[lane]
            + z[(size_t)b * F_OUT + lane] * Wlin[64 + lane];
    #pragma unroll
    for (int off = 32; off > 0; off >>= 1) v += __shfl_down(v, off, 64);
    if (lane == 0) out[p] = 1.0f / (1.0f + expf(-(v + blin[0])));
}

// ---------------------------------------------------------------------------

extern "C" void kernel_launch(void* const* d_in, const int* in_sizes, int n_in,
                              void* d_out, int out_size, void* d_ws, size_t ws_size,
                              hipStream_t stream) {
    const float* x          = (const float*)d_in[0];
    const int*   edge_index = (const int*)d_in[1];
    const int*   edge_pairs = (const int*)d_in[2];
    const float* W1l        = (const float*)d_in[3];
    const float* b1         = (const float*)d_in[4];
    const float* W1r        = (const float*)d_in[5];
    const float* W2l        = (const float*)d_in[6];
    const float* b2         = (const float*)d_in[7];
    const float* W2r        = (const float*)d_in[8];
    const float* Wlin       = (const float*)d_in[9];
    const float* blin       = (const float*)d_in[10];
    float* out = (float*)d_out;

    const int N = in_sizes[0] / F_IN;      // 50000
    const int E = in_sizes[1] / 2;         // 800000
    const int P = in_sizes[2] / 2;         // 200000

    const int* src = edge_index;
    const int* dst = edge_index + E;
    const int* ps  = edge_pairs;
    const int* pd  = edge_pairs + P;

    float* A = (float*)d_ws;               // mean_x, then tu
    float* B = A + (size_t)N * 128;        // h, then z (first N*64)
    int* deg     = (int*)(B + (size_t)N * 128);
    int* rowptr  = deg + N;
    int* cursor  = rowptr + N + 1;
    int* esrc    = cursor + N;
    int* partials= esrc + E;

    const int scan_blocks = (N + 255) / 256;   // 196

    // CSR build
    hipMemsetAsync(deg, 0, (size_t)N * sizeof(int), stream);
    hist_kernel<<<(E + 255) / 256, 256, 0, stream>>>(dst, deg, E);
    partial_sum_kernel<<<scan_blocks, 256, 0, stream>>>(deg, partials, N);
    scan_partials_kernel<<<1, 256, 0, stream>>>(partials, scan_blocks);
    scan_final_kernel<<<scan_blocks, 256, 0, stream>>>(deg, partials, rowptr, cursor, N);
    fill_kernel<<<(E + 255) / 256, 256, 0, stream>>>(src, dst, cursor, esrc, E);

    // layer 1
    agg_mean_x_kernel<<<(N + 3) / 4, 256, 0, stream>>>(x, rowptr, esrc, A, N);
    gemm1_kernel<<<(N + 31) / 32, 256, 0, stream>>>(A, x, W1l, W1r, b1, B, N);

    // layer 2 (transform first, aggregate 64-dim t)
    gemm2_kernel<<<(N + 31) / 32, 256, 0, stream>>>(B, W2l, W2r, A, N);
    agg_mean_t_kernel<<<(N + 3) / 4, 256, 0, stream>>>(A, rowptr, esrc, b2, B, N);

    // link prediction (z lives in B)
    link_kernel<<<(P + 3) / 4, 256, 0, stream>>>(B, ps, pd, Wlin, blin, out, P);
}

// Round 4
// 386.644 us; speedup vs baseline: 2.9476x; 1.2027x over previous
//
#include <hip/hip_runtime.h>
#include <math.h>

// ---------------------------------------------------------------------------
// 2-layer GraphSAGE (mean aggr) + link predictor, fp32. CSR-gather version.
//
// Pipeline:
//   hist(deg) -> 3-phase scan(rowptr,cursor) -> fill(esrc)   [CSR build]
//   agg1: mean_x = mean_{j in N(i)} x_j                      (4-wide MLP gather)
//   GEMM1: h = relu([mean_x | x] @ [W1l; W1r] + b1)          (tiled LDS GEMM)
//   GEMM2: [t|u] = h @ [W2l | W2r]                           (tiled LDS GEMM)
//   agg2:  z = mean_{j}(t_j) + u_i + b2                      (4-wide MLP gather)
//   link:  sigmoid(dot)
//
// ws: A[N*128] | B[N*128] | deg | rowptr | cursor | esrc | partials
// ---------------------------------------------------------------------------

#define F_IN 128
#define F_OUT 64

// ---- CSR build -------------------------------------------------------------

__global__ void hist_kernel(const int* __restrict__ dst, int* __restrict__ deg, int E) {
    int e = blockIdx.x * blockDim.x + threadIdx.x;
    if (e < E) atomicAdd(&deg[dst[e]], 1);
}

// phase B: per-block sum of 256 deg entries
__global__ void partial_sum_kernel(const int* __restrict__ deg,
                                   int* __restrict__ partials, int N) {
    __shared__ int ws[4];
    int i = blockIdx.x * 256 + threadIdx.x;
    int t = threadIdx.x;
    int v = (i < N) ? deg[i] : 0;
    #pragma unroll
    for (int off = 32; off > 0; off >>= 1) v += __shfl_down(v, off, 64);
    if ((t & 63) == 0) ws[t >> 6] = v;
    __syncthreads();
    if (t == 0) partials[blockIdx.x] = ws[0] + ws[1] + ws[2] + ws[3];
}

// phase C: single small block, exclusive scan of partials in place (nb <= 256)
__global__ void scan_partials_kernel(int* __restrict__ partials, int nb) {
    __shared__ int buf[256];
    int t = threadIdx.x;
    int v = (t < nb) ? partials[t] : 0;
    buf[t] = v;
    __syncthreads();
    for (int off = 1; off < 256; off <<= 1) {
        int u = (t >= off) ? buf[t - off] : 0;
        __syncthreads();
        buf[t] += u;
        __syncthreads();
    }
    if (t < nb) partials[t] = (t == 0) ? 0 : buf[t - 1];
}

// phase D: per-block scan + block offset -> rowptr & cursor
__global__ void scan_final_kernel(const int* __restrict__ deg,
                                  const int* __restrict__ blockoff,
                                  int* __restrict__ rowptr,
                                  int* __restrict__ cursor, int N) {
    __shared__ int buf[256];
    int i = blockIdx.x * 256 + threadIdx.x;
    int t = threadIdx.x;
    int v = (i < N) ? deg[i] : 0;
    buf[t] = v;
    __syncthreads();
    for (int off = 1; off < 256; off <<= 1) {
        int u = (t >= off) ? buf[t - off] : 0;
        __syncthreads();
        buf[t] += u;
        __syncthreads();
    }
    int excl = blockoff[blockIdx.x] + ((t == 0) ? 0 : buf[t - 1]);
    if (i < N) {
        rowptr[i] = excl;
        cursor[i] = excl;
        if (i == N - 1) rowptr[N] = excl + v;
    }
}

__global__ void fill_kernel(const int* __restrict__ src, const int* __restrict__ dst,
                            int* __restrict__ cursor, int* __restrict__ esrc, int E) {
    int e = blockIdx.x * blockDim.x + threadIdx.x;
    if (e < E) {
        int pos = atomicAdd(&cursor[dst[e]], 1);
        esrc[pos] = src[e];
    }
}

// ---- aggregation (gather, 4-wide for memory-level parallelism) -------------

// mean over 128 features: one wave per node, float2 per lane, 4 edges/iter
__global__ void agg_mean_x_kernel(const float* __restrict__ x,
                                  const int* __restrict__ rowptr,
                                  const int* __restrict__ esrc,
                                  float* __restrict__ mean, int N) {
    int node = blockIdx.x * 4 + (threadIdx.x >> 6);
    int lane = threadIdx.x & 63;
    if (node >= N) return;
    int s0 = rowptr[node], s1 = rowptr[node + 1];
    float2* mp = (float2*)(mean + (size_t)node * 128 + lane * 2);
    if (s0 == s1) { *mp = make_float2(0.f, 0.f); return; }
    float ax0 = 0.f, ay0 = 0.f, ax1 = 0.f, ay1 = 0.f;
    float ax2 = 0.f, ay2 = 0.f, ax3 = 0.f, ay3 = 0.f;
    for (int k = s0; k < s1; k += 4) {
        int k1 = k + 1, k2 = k + 2, k3 = k + 3;
        int i0 = esrc[k];
        int i1 = esrc[k1 < s1 ? k1 : k];
        int i2 = esrc[k2 < s1 ? k2 : k];
        int i3 = esrc[k3 < s1 ? k3 : k];
        float m1 = (k1 < s1) ? 1.f : 0.f;
        float m2 = (k2 < s1) ? 1.f : 0.f;
        float m3 = (k3 < s1) ? 1.f : 0.f;
        float2 v0 = *(const float2*)(x + (size_t)i0 * 128 + lane * 2);
        float2 v1 = *(const float2*)(x + (size_t)i1 * 128 + lane * 2);
        float2 v2 = *(const float2*)(x + (size_t)i2 * 128 + lane * 2);
        float2 v3 = *(const float2*)(x + (size_t)i3 * 128 + lane * 2);
        ax0 += v0.x;      ay0 += v0.y;
        ax1 += v1.x * m1; ay1 += v1.y * m1;
        ax2 += v2.x * m2; ay2 += v2.y * m2;
        ax3 += v3.x * m3; ay3 += v3.y * m3;
    }
    float inv = 1.0f / (float)(s1 - s0);
    float ax = (ax0 + ax1) + (ax2 + ax3);
    float ay = (ay0 + ay1) + (ay2 + ay3);
    *mp = make_float2(ax * inv, ay * inv);
}

// mean over t (cols 0..63 of tu) + u (cols 64..127) + b2 -> z[N,64]
__global__ void agg_mean_t_kernel(const float* __restrict__ tu,
                                  const int* __restrict__ rowptr,
                                  const int* __restrict__ esrc,
                                  const float* __restrict__ b2,
                                  float* __restrict__ z, int N) {
    int node = blockIdx.x * 4 + (threadIdx.x >> 6);
    int lane = threadIdx.x & 63;
    if (node >= N) return;
    int s0 = rowptr[node], s1 = rowptr[node + 1];
    float selfu = tu[(size_t)node * 128 + 64 + lane] + b2[lane];
    if (s0 == s1) { z[(size_t)node * 64 + lane] = selfu; return; }
    float a0 = 0.f, a1 = 0.f, a2 = 0.f, a3 = 0.f;
    for (int k = s0; k < s1; k += 4) {
        int k1 = k + 1, k2 = k + 2, k3 = k + 3;
        int i0 = esrc[k];
        int i1 = esrc[k1 < s1 ? k1 : k];
        int i2 = esrc[k2 < s1 ? k2 : k];
        int i3 = esrc[k3 < s1 ? k3 : k];
        float m1 = (k1 < s1) ? 1.f : 0.f;
        float m2 = (k2 < s1) ? 1.f : 0.f;
        float m3 = (k3 < s1) ? 1.f : 0.f;
        float v0 = tu[(size_t)i0 * 128 + lane];
        float v1 = tu[(size_t)i1 * 128 + lane];
        float v2 = tu[(size_t)i2 * 128 + lane];
        float v3 = tu[(size_t)i3 * 128 + lane];
        a0 += v0;
        a1 += v1 * m1;
        a2 += v2 * m2;
        a3 += v3 * m3;
    }
    float inv = 1.0f / (float)(s1 - s0);
    float acc = (a0 + a1) + (a2 + a3);
    z[(size_t)node * 64 + lane] = acc * inv + selfu;
}

// ---- tiled GEMMs -----------------------------------------------------------
// BM=32, BK=32, output width 128, 256 threads, each computes 4x4 micro-tile.

__global__ __launch_bounds__(256)
void gemm1_kernel(const float* __restrict__ mean, const float* __restrict__ x,
                  const float* __restrict__ W1l, const float* __restrict__ W1r,
                  const float* __restrict__ b1, float* __restrict__ h, int N) {
    __shared__ float sA[32][36];
    __shared__ float sB[32][128];
    int tid = threadIdx.x;
    int tx = tid & 31;
    int ty = tid >> 5;
    int row0 = blockIdx.x * 32;
    int lr = tid >> 3;            // 0..31 sA row
    int lk = (tid & 7) * 4;       // sA k offset
    int wc = (tid & 31) * 4;      // sB col
    int wr = tid >> 5;            // sB base row
    float acc[4][4] = {};
    for (int kb = 0; kb < 8; ++kb) {
        const float* srcp = (kb < 4) ? mean : x;
        int koff = (kb & 3) * 32;
        int gi = row0 + lr;
        float4 av = make_float4(0.f, 0.f, 0.f, 0.f);
        if (gi < N) av = *(const float4*)(srcp + (size_t)gi * 128 + koff + lk);
        *(float4*)&sA[lr][lk] = av;
        const float* W = (kb < 4) ? W1l : W1r;
        #pragma unroll
        for (int i = 0; i < 4; ++i) {
            int r = wr + 8 * i;
            *(float4*)&sB[r][wc] = *(const float4*)(W + (size_t)(koff + r) * 128 + wc);
        }
        __syncthreads();
        #pragma unroll
        for (int kk = 0; kk < 32; ++kk) {
            float a[4], b[4];
            #pragma unroll
            for (int i = 0; i < 4; ++i) a[i] = sA[ty * 4 + i][kk];
            #pragma unroll
            for (int c = 0; c < 4; ++c) b[c] = sB[kk][tx + 32 * c];
            #pragma unroll
            for (int i = 0; i < 4; ++i)
                #pragma unroll
                for (int c = 0; c < 4; ++c)
                    acc[i][c] += a[i] * b[c];
        }
        __syncthreads();
    }
    #pragma unroll
    for (int i = 0; i < 4; ++i) {
        int gi = row0 + ty * 4 + i;
        if (gi >= N) continue;
        #pragma unroll
        for (int c = 0; c < 4; ++c) {
            int col = tx + 32 * c;
            h[(size_t)gi * 128 + col] = fmaxf(acc[i][c] + b1[col], 0.f);
        }
    }
}

// tu = h @ [W2l | W2r]  (K=128; W2l,W2r are [128,64])
__global__ __launch_bounds__(256)
void gemm2_kernel(const float* __restrict__ h,
                  const float* __restrict__ W2l, const float* __restrict__ W2r,
                  float* __restrict__ tu, int N) {
    __shared__ float sA[32][36];
    __shared__ float sB[32][128];
    int tid = threadIdx.x;
    int tx = tid & 31;
    int ty = tid >> 5;
    int row0 = blockIdx.x * 32;
    int lr = tid >> 3;
    int lk = (tid & 7) * 4;
    int wc = (tid & 31) * 4;
    int wr = tid >> 5;
    float acc[4][4] = {};
    for (int kb = 0; kb < 4; ++kb) {
        int koff = kb * 32;
        int gi = row0 + lr;
        float4 av = make_float4(0.f, 0.f, 0.f, 0.f);
        if (gi < N) av = *(const float4*)(h + (size_t)gi * 128 + koff + lk);
        *(float4*)&sA[lr][lk] = av;
        #pragma unroll
        for (int i = 0; i < 4; ++i) {
            int r = wr + 8 * i;
            int k = koff + r;
            float4 wv;
            if (wc < 64) wv = *(const float4*)(W2l + (size_t)k * 64 + wc);
            else         wv = *(const float4*)(W2r + (size_t)k * 64 + (wc - 64));
            *(float4*)&sB[r][wc] = wv;
        }
        __syncthreads();
        #pragma unroll
        for (int kk = 0; kk < 32; ++kk) {
            float a[4], b[4];
            #pragma unroll
            for (int i = 0; i < 4; ++i) a[i] = sA[ty * 4 + i][kk];
            #pragma unroll
            for (int c = 0; c < 4; ++c) b[c] = sB[kk][tx + 32 * c];
            #pragma unroll
            for (int i = 0; i < 4; ++i)
                #pragma unroll
                for (int c = 0; c < 4; ++c)
                    acc[i][c] += a[i] * b[c];
        }
        __syncthreads();
    }
    #pragma unroll
    for (int i = 0; i < 4; ++i) {
        int gi = row0 + ty * 4 + i;
        if (gi >= N) continue;
        #pragma unroll
        for (int c = 0; c < 4; ++c) {
            int col = tx + 32 * c;
            tu[(size_t)gi * 128 + col] = acc[i][c];
        }
    }
}

// ---- link prediction -------------------------------------------------------

__global__ void link_kernel(const float* __restrict__ z,
                            const int* __restrict__ ps,
                            const int* __restrict__ pd,
                            const float* __restrict__ Wlin,
                            const float* __restrict__ blin,
                            float* __restrict__ out, int P) {
    int p = blockIdx.x * 4 + (threadIdx.x >> 6);
    int lane = threadIdx.x & 63;
    if (p >= P) return;
    int a = ps[p];
    int b = pd[p];
    float v = z[(size_t)a * F_OUT + lane] * Wlin[lane]
            + z[(size_t)b * F_OUT + lane] * Wlin[64 + lane];
    #pragma unroll
    for (int off = 32; off > 0; off >>= 1) v += __shfl_down(v, off, 64);
    if (lane == 0) out[p] = 1.0f / (1.0f + expf(-(v + blin[0])));
}

// ---------------------------------------------------------------------------

extern "C" void kernel_launch(void* const* d_in, const int* in_sizes, int n_in,
                              void* d_out, int out_size, void* d_ws, size_t ws_size,
                              hipStream_t stream) {
    const float* x          = (const float*)d_in[0];
    const int*   edge_index = (const int*)d_in[1];
    const int*   edge_pairs = (const int*)d_in[2];
    const float* W1l        = (const float*)d_in[3];
    const float* b1         = (const float*)d_in[4];
    const float* W1r        = (const float*)d_in[5];
    const float* W2l        = (const float*)d_in[6];
    const float* b2         = (const float*)d_in[7];
    const float* W2r        = (const float*)d_in[8];
    const float* Wlin       = (const float*)d_in[9];
    const float* blin       = (const float*)d_in[10];
    float* out = (float*)d_out;

    const int N = in_sizes[0] / F_IN;      // 50000
    const int E = in_sizes[1] / 2;         // 800000
    const int P = in_sizes[2] / 2;         // 200000

    const int* src = edge_index;
    const int* dst = edge_index + E;
    const int* ps  = edge_pairs;
    const int* pd  = edge_pairs + P;

    float* A = (float*)d_ws;               // mean_x, then tu
    float* B = A + (size_t)N * 128;        // h, then z (first N*64)
    int* deg     = (int*)(B + (size_t)N * 128);
    int* rowptr  = deg + N;
    int* cursor  = rowptr + N + 1;
    int* esrc    = cursor + N;
    int* partials= esrc + E;

    const int scan_blocks = (N + 255) / 256;   // 196

    // CSR build
    hipMemsetAsync(deg, 0, (size_t)N * sizeof(int), stream);
    hist_kernel<<<(E + 255) / 256, 256, 0, stream>>>(dst, deg, E);
    partial_sum_kernel<<<scan_blocks, 256, 0, stream>>>(deg, partials, N);
    scan_partials_kernel<<<1, 256, 0, stream>>>(partials, scan_blocks);
    scan_final_kernel<<<scan_blocks, 256, 0, stream>>>(deg, partials, rowptr, cursor, N);
    fill_kernel<<<(E + 255) / 256, 256, 0, stream>>>(src, dst, cursor, esrc, E);

    // layer 1
    agg_mean_x_kernel<<<(N + 3) / 4, 256, 0, stream>>>(x, rowptr, esrc, A, N);
    gemm1_kernel<<<(N + 31) / 32, 256, 0, stream>>>(A, x, W1l, W1r, b1, B, N);

    // layer 2 (transform first, aggregate 64-dim t)
    gemm2_kernel<<<(N + 31) / 32, 256, 0, stream>>>(B, W2l, W2r, A, N);
    agg_mean_t_kernel<<<(N + 3) / 4, 256, 0, stream>>>(A, rowptr, esrc, b2, B, N);

    // link prediction (z lives in B)
    link_kernel<<<(P + 3) / 4, 256, 0, stream>>>(B, ps, pd, Wlin, blin, out, P);
}

// Round 5
// 377.685 us; speedup vs baseline: 3.0175x; 1.0237x over previous
//
#include <hip/hip_runtime.h>
#include <math.h>

// ---------------------------------------------------------------------------
// 2-layer GraphSAGE (mean aggr) + link predictor, fp32. CSR-gather version.
//
// Pipeline:
//   hist(deg) -> 3-phase scan(rowptr,cursor) -> fill(esrc)   [CSR build]
//   agg1: mean_x = mean_{j in N(i)} x_j                      (4-wide MLP gather)
//   GEMM1: h = relu([mean_x | x] @ [W1l; W1r] + b1)          (64x128 tile, b128)
//   GEMM2: [t|u] = h @ [W2l | W2r]                           (64x128 tile, b128)
//   agg2:  z = mean_{j}(t_j) + u_i + b2                      (4-wide MLP gather)
//   link:  sigmoid(dot)
//
// ws: A[N*128] | B[N*128] | deg | rowptr | cursor | esrc | partials
// ---------------------------------------------------------------------------

#define F_IN 128
#define F_OUT 64
#define LDA 68   // sAT leading dim (m), multiple of 4 keeps float4 alignment

// ---- CSR build -------------------------------------------------------------

__global__ void hist_kernel(const int* __restrict__ dst, int* __restrict__ deg, int E) {
    int e = blockIdx.x * blockDim.x + threadIdx.x;
    if (e < E) atomicAdd(&deg[dst[e]], 1);
}

__global__ void partial_sum_kernel(const int* __restrict__ deg,
                                   int* __restrict__ partials, int N) {
    __shared__ int ws[4];
    int i = blockIdx.x * 256 + threadIdx.x;
    int t = threadIdx.x;
    int v = (i < N) ? deg[i] : 0;
    #pragma unroll
    for (int off = 32; off > 0; off >>= 1) v += __shfl_down(v, off, 64);
    if ((t & 63) == 0) ws[t >> 6] = v;
    __syncthreads();
    if (t == 0) partials[blockIdx.x] = ws[0] + ws[1] + ws[2] + ws[3];
}

__global__ void scan_partials_kernel(int* __restrict__ partials, int nb) {
    __shared__ int buf[256];
    int t = threadIdx.x;
    int v = (t < nb) ? partials[t] : 0;
    buf[t] = v;
    __syncthreads();
    for (int off = 1; off < 256; off <<= 1) {
        int u = (t >= off) ? buf[t - off] : 0;
        __syncthreads();
        buf[t] += u;
        __syncthreads();
    }
    if (t < nb) partials[t] = (t == 0) ? 0 : buf[t - 1];
}

__global__ void scan_final_kernel(const int* __restrict__ deg,
                                  const int* __restrict__ blockoff,
                                  int* __restrict__ rowptr,
                                  int* __restrict__ cursor, int N) {
    __shared__ int buf[256];
    int i = blockIdx.x * 256 + threadIdx.x;
    int t = threadIdx.x;
    int v = (i < N) ? deg[i] : 0;
    buf[t] = v;
    __syncthreads();
    for (int off = 1; off < 256; off <<= 1) {
        int u = (t >= off) ? buf[t - off] : 0;
        __syncthreads();
        buf[t] += u;
        __syncthreads();
    }
    int excl = blockoff[blockIdx.x] + ((t == 0) ? 0 : buf[t - 1]);
    if (i < N) {
        rowptr[i] = excl;
        cursor[i] = excl;
        if (i == N - 1) rowptr[N] = excl + v;
    }
}

__global__ void fill_kernel(const int* __restrict__ src, const int* __restrict__ dst,
                            int* __restrict__ cursor, int* __restrict__ esrc, int E) {
    int e = blockIdx.x * blockDim.x + threadIdx.x;
    if (e < E) {
        int pos = atomicAdd(&cursor[dst[e]], 1);
        esrc[pos] = src[e];
    }
}

// ---- aggregation (gather, 4-wide for memory-level parallelism) -------------

__global__ void agg_mean_x_kernel(const float* __restrict__ x,
                                  const int* __restrict__ rowptr,
                                  const int* __restrict__ esrc,
                                  float* __restrict__ mean, int N) {
    int node = blockIdx.x * 4 + (threadIdx.x >> 6);
    int lane = threadIdx.x & 63;
    if (node >= N) return;
    int s0 = rowptr[node], s1 = rowptr[node + 1];
    float2* mp = (float2*)(mean + (size_t)node * 128 + lane * 2);
    if (s0 == s1) { *mp = make_float2(0.f, 0.f); return; }
    float ax0 = 0.f, ay0 = 0.f, ax1 = 0.f, ay1 = 0.f;
    float ax2 = 0.f, ay2 = 0.f, ax3 = 0.f, ay3 = 0.f;
    for (int k = s0; k < s1; k += 4) {
        int k1 = k + 1, k2 = k + 2, k3 = k + 3;
        int i0 = esrc[k];
        int i1 = esrc[k1 < s1 ? k1 : k];
        int i2 = esrc[k2 < s1 ? k2 : k];
        int i3 = esrc[k3 < s1 ? k3 : k];
        float m1 = (k1 < s1) ? 1.f : 0.f;
        float m2 = (k2 < s1) ? 1.f : 0.f;
        float m3 = (k3 < s1) ? 1.f : 0.f;
        float2 v0 = *(const float2*)(x + (size_t)i0 * 128 + lane * 2);
        float2 v1 = *(const float2*)(x + (size_t)i1 * 128 + lane * 2);
        float2 v2 = *(const float2*)(x + (size_t)i2 * 128 + lane * 2);
        float2 v3 = *(const float2*)(x + (size_t)i3 * 128 + lane * 2);
        ax0 += v0.x;      ay0 += v0.y;
        ax1 += v1.x * m1; ay1 += v1.y * m1;
        ax2 += v2.x * m2; ay2 += v2.y * m2;
        ax3 += v3.x * m3; ay3 += v3.y * m3;
    }
    float inv = 1.0f / (float)(s1 - s0);
    float ax = (ax0 + ax1) + (ax2 + ax3);
    float ay = (ay0 + ay1) + (ay2 + ay3);
    *mp = make_float2(ax * inv, ay * inv);
}

__global__ void agg_mean_t_kernel(const float* __restrict__ tu,
                                  const int* __restrict__ rowptr,
                                  const int* __restrict__ esrc,
                                  const float* __restrict__ b2,
                                  float* __restrict__ z, int N) {
    int node = blockIdx.x * 4 + (threadIdx.x >> 6);
    int lane = threadIdx.x & 63;
    if (node >= N) return;
    int s0 = rowptr[node], s1 = rowptr[node + 1];
    float selfu = tu[(size_t)node * 128 + 64 + lane] + b2[lane];
    if (s0 == s1) { z[(size_t)node * 64 + lane] = selfu; return; }
    float a0 = 0.f, a1 = 0.f, a2 = 0.f, a3 = 0.f;
    for (int k = s0; k < s1; k += 4) {
        int k1 = k + 1, k2 = k + 2, k3 = k + 3;
        int i0 = esrc[k];
        int i1 = esrc[k1 < s1 ? k1 : k];
        int i2 = esrc[k2 < s1 ? k2 : k];
        int i3 = esrc[k3 < s1 ? k3 : k];
        float m1 = (k1 < s1) ? 1.f : 0.f;
        float m2 = (k2 < s1) ? 1.f : 0.f;
        float m3 = (k3 < s1) ? 1.f : 0.f;
        float v0 = tu[(size_t)i0 * 128 + lane];
        float v1 = tu[(size_t)i1 * 128 + lane];
        float v2 = tu[(size_t)i2 * 128 + lane];
        float v3 = tu[(size_t)i3 * 128 + lane];
        a0 += v0;
        a1 += v1 * m1;
        a2 += v2 * m2;
        a3 += v3 * m3;
    }
    float inv = 1.0f / (float)(s1 - s0);
    float acc = (a0 + a1) + (a2 + a3);
    z[(size_t)node * 64 + lane] = acc * inv + selfu;
}

// ---- tiled GEMMs -----------------------------------------------------------
// 64x128 tile, BK=32, 256 threads, 8x4 micro-tile, all-b128 LDS traffic.
// sAT is k-major (transposed) so A fragments are contiguous float4s.

__global__ __launch_bounds__(256)
void gemm1_kernel(const float* __restrict__ mean, const float* __restrict__ x,
                  const float* __restrict__ W1l, const float* __restrict__ W1r,
                  const float* __restrict__ b1, float* __restrict__ h, int N) {
    __shared__ float sAT[32][LDA];     // [k][m]
    __shared__ float sB[32][128];      // [k][n]
    int tid = threadIdx.x;
    int tx = tid & 31;                 // cols tx*4 .. tx*4+3
    int ty = tid >> 5;                 // rows ty*8 .. ty*8+7
    int row0 = blockIdx.x * 64;
    float acc[8][4] = {};
    for (int kb = 0; kb < 8; ++kb) {
        const float* srcp = (kb < 4) ? mean : x;
        const float* W    = (kb < 4) ? W1l  : W1r;
        int koff = (kb & 3) * 32;
        // stage A (64 rows x 32 k), transposed into sAT
        #pragma unroll
        for (int s = 0; s < 2; ++s) {
            int slot = tid + s * 256;      // 512 float4 slots
            int r  = slot >> 3;            // 0..63
            int k4 = (slot & 7) * 4;
            int gi = row0 + r;
            float4 av = make_float4(0.f, 0.f, 0.f, 0.f);
            if (gi < N) av = *(const float4*)(srcp + (size_t)gi * 128 + koff + k4);
            sAT[k4 + 0][r] = av.x;
            sAT[k4 + 1][r] = av.y;
            sAT[k4 + 2][r] = av.z;
            sAT[k4 + 3][r] = av.w;
        }
        // stage B (32 k x 128 n)
        #pragma unroll
        for (int s = 0; s < 4; ++s) {
            int slot = tid + s * 256;      // 1024 float4 slots
            int r  = slot >> 5;            // 0..31
            int c4 = (slot & 31) * 4;
            *(float4*)&sB[r][c4] = *(const float4*)(W + (size_t)(koff + r) * 128 + c4);
        }
        __syncthreads();
        #pragma unroll
        for (int kk = 0; kk < 32; ++kk) {
            float4 a0 = *(const float4*)&sAT[kk][ty * 8];
            float4 a1 = *(const float4*)&sAT[kk][ty * 8 + 4];
            float4 bv = *(const float4*)&sB[kk][tx * 4];
            float a[8] = {a0.x, a0.y, a0.z, a0.w, a1.x, a1.y, a1.z, a1.w};
            float b[4] = {bv.x, bv.y, bv.z, bv.w};
            #pragma unroll
            for (int i = 0; i < 8; ++i)
                #pragma unroll
                for (int c = 0; c < 4; ++c)
                    acc[i][c] += a[i] * b[c];
        }
        __syncthreads();
    }
    float4 bias = *(const float4*)&b1[tx * 4];
    #pragma unroll
    for (int i = 0; i < 8; ++i) {
        int gi = row0 + ty * 8 + i;
        if (gi >= N) continue;
        float4 o;
        o.x = fmaxf(acc[i][0] + bias.x, 0.f);
        o.y = fmaxf(acc[i][1] + bias.y, 0.f);
        o.z = fmaxf(acc[i][2] + bias.z, 0.f);
        o.w = fmaxf(acc[i][3] + bias.w, 0.f);
        *(float4*)(h + (size_t)gi * 128 + tx * 4) = o;
    }
}

// tu = h @ [W2l | W2r]  (K=128; W2l,W2r are [128,64])
__global__ __launch_bounds__(256)
void gemm2_kernel(const float* __restrict__ h,
                  const float* __restrict__ W2l, const float* __restrict__ W2r,
                  float* __restrict__ tu, int N) {
    __shared__ float sAT[32][LDA];
    __shared__ float sB[32][128];
    int tid = threadIdx.x;
    int tx = tid & 31;
    int ty = tid >> 5;
    int row0 = blockIdx.x * 64;
    float acc[8][4] = {};
    for (int kb = 0; kb < 4; ++kb) {
        int koff = kb * 32;
        #pragma unroll
        for (int s = 0; s < 2; ++s) {
            int slot = tid + s * 256;
            int r  = slot >> 3;
            int k4 = (slot & 7) * 4;
            int gi = row0 + r;
            float4 av = make_float4(0.f, 0.f, 0.f, 0.f);
            if (gi < N) av = *(const float4*)(h + (size_t)gi * 128 + koff + k4);
            sAT[k4 + 0][r] = av.x;
            sAT[k4 + 1][r] = av.y;
            sAT[k4 + 2][r] = av.z;
            sAT[k4 + 3][r] = av.w;
        }
        #pragma unroll
        for (int s = 0; s < 4; ++s) {
            int slot = tid + s * 256;
            int r  = slot >> 5;
            int c4 = (slot & 31) * 4;
            int k = koff + r;
            float4 wv;
            if (c4 < 64) wv = *(const float4*)(W2l + (size_t)k * 64 + c4);
            else         wv = *(const float4*)(W2r + (size_t)k * 64 + (c4 - 64));
            *(float4*)&sB[r][c4] = wv;
        }
        __syncthreads();
        #pragma unroll
        for (int kk = 0; kk < 32; ++kk) {
            float4 a0 = *(const float4*)&sAT[kk][ty * 8];
            float4 a1 = *(const float4*)&sAT[kk][ty * 8 + 4];
            float4 bv = *(const float4*)&sB[kk][tx * 4];
            float a[8] = {a0.x, a0.y, a0.z, a0.w, a1.x, a1.y, a1.z, a1.w};
            float b[4] = {bv.x, bv.y, bv.z, bv.w};
            #pragma unroll
            for (int i = 0; i < 8; ++i)
                #pragma unroll
                for (int c = 0; c < 4; ++c)
                    acc[i][c] += a[i] * b[c];
        }
        __syncthreads();
    }
    #pragma unroll
    for (int i = 0; i < 8; ++i) {
        int gi = row0 + ty * 8 + i;
        if (gi >= N) continue;
        float4 o = make_float4(acc[i][0], acc[i][1], acc[i][2], acc[i][3]);
        *(float4*)(tu + (size_t)gi * 128 + tx * 4) = o;
    }
}

// ---- link prediction -------------------------------------------------------

__global__ void link_kernel(const float* __restrict__ z,
                            const int* __restrict__ ps,
                            const int* __restrict__ pd,
                            const float* __restrict__ Wlin,
                            const float* __restrict__ blin,
                            float* __restrict__ out, int P) {
    int p = blockIdx.x * 4 + (threadIdx.x >> 6);
    int lane = threadIdx.x & 63;
    if (p >= P) return;
    int a = ps[p];
    int b = pd[p];
    float v = z[(size_t)a * F_OUT + lane] * Wlin[lane]
            + z[(size_t)b * F_OUT + lane] * Wlin[64 + lane];
    #pragma unroll
    for (int off = 32; off > 0; off >>= 1) v += __shfl_down(v, off, 64);
    if (lane == 0) out[p] = 1.0f / (1.0f + expf(-(v + blin[0])));
}

// ---------------------------------------------------------------------------

extern "C" void kernel_launch(void* const* d_in, const int* in_sizes, int n_in,
                              void* d_out, int out_size, void* d_ws, size_t ws_size,
                              hipStream_t stream) {
    const float* x          = (const float*)d_in[0];
    const int*   edge_index = (const int*)d_in[1];
    const int*   edge_pairs = (const int*)d_in[2];
    const float* W1l        = (const float*)d_in[3];
    const float* b1         = (const float*)d_in[4];
    const float* W1r        = (const float*)d_in[5];
    const float* W2l        = (const float*)d_in[6];
    const float* b2         = (const float*)d_in[7];
    const float* W2r        = (const float*)d_in[8];
    const float* Wlin       = (const float*)d_in[9];
    const float* blin       = (const float*)d_in[10];
    float* out = (float*)d_out;

    const int N = in_sizes[0] / F_IN;      // 50000
    const int E = in_sizes[1] / 2;         // 800000
    const int P = in_sizes[2] / 2;         // 200000

    const int* src = edge_index;
    const int* dst = edge_index + E;
    const int* ps  = edge_pairs;
    const int* pd  = edge_pairs + P;

    float* A = (float*)d_ws;               // mean_x, then tu
    float* B = A + (size_t)N * 128;        // h, then z (first N*64)
    int* deg     = (int*)(B + (size_t)N * 128);
    int* rowptr  = deg + N;
    int* cursor  = rowptr + N + 1;
    int* esrc    = cursor + N;
    int* partials= esrc + E;

    const int scan_blocks = (N + 255) / 256;   // 196

    // CSR build
    hipMemsetAsync(deg, 0, (size_t)N * sizeof(int), stream);
    hist_kernel<<<(E + 255) / 256, 256, 0, stream>>>(dst, deg, E);
    partial_sum_kernel<<<scan_blocks, 256, 0, stream>>>(deg, partials, N);
    scan_partials_kernel<<<1, 256, 0, stream>>>(partials, scan_blocks);
    scan_final_kernel<<<scan_blocks, 256, 0, stream>>>(deg, partials, rowptr, cursor, N);
    fill_kernel<<<(E + 255) / 256, 256, 0, stream>>>(src, dst, cursor, esrc, E);

    // layer 1
    agg_mean_x_kernel<<<(N + 3) / 4, 256, 0, stream>>>(x, rowptr, esrc, A, N);
    gemm1_kernel<<<(N + 63) / 64, 256, 0, stream>>>(A, x, W1l, W1r, b1, B, N);

    // layer 2 (transform first, aggregate 64-dim t)
    gemm2_kernel<<<(N + 63) / 64, 256, 0, stream>>>(B, W2l, W2r, A, N);
    agg_mean_t_kernel<<<(N + 3) / 4, 256, 0, stream>>>(A, rowptr, esrc, b2, B, N);

    // link prediction (z lives in B)
    link_kernel<<<(P + 3) / 4, 256, 0, stream>>>(B, ps, pd, Wlin, blin, out, P);
}

// Round 6
// 345.070 us; speedup vs baseline: 3.3027x; 1.0945x over previous
//
#include <hip/hip_runtime.h>
#include <math.h>

// ---------------------------------------------------------------------------
// 2-layer GraphSAGE (mean aggr) + link predictor. bf16 MFMA version.
//
//   cast x->bf16, cast+transpose weights -> Wt[n][k] bf16
//   CSR build (hist -> 3-phase scan -> fill)
//   agg1: meanh = mean_{j} xh_j                      (bf16 gather, fp32 acc)
//   GEMM1: h = relu([meanh|xh] @ W1 + b1)            (MFMA 16x16x32 bf16)
//   GEMM2: tu = h @ [W2l|W2r]                        (MFMA 16x16x32 bf16)
//   agg2:  z = mean_{j}(t_j) + u_i + b2              (bf16 gather, fp32 out)
//   link:  sigmoid(dot)                              (fp32)
//
// ws: xh[N*128] | meanh[N*128 bf16, reused as z fp32 N*64] | h[N*128] |
//     tu[N*128] | W1t | W2t | deg | rowptr | cursor | esrc | partials
// ---------------------------------------------------------------------------

#define F_OUT 64

typedef __attribute__((ext_vector_type(8))) short bf16x8;
typedef __attribute__((ext_vector_type(4))) float f32x4;
typedef unsigned int uint32;
typedef unsigned short ushort16;

__device__ __forceinline__ ushort16 f2bf(float f) {
    uint32 u = __float_as_uint(f);
    uint32 r = u + 0x7FFFu + ((u >> 16) & 1u);   // round-to-nearest-even
    return (ushort16)(r >> 16);
}
__device__ __forceinline__ float bf2f(ushort16 u) {
    return __uint_as_float(((uint32)u) << 16);
}

// ---- casts -----------------------------------------------------------------

__global__ void cast_x_kernel(const float* __restrict__ x, uint32* __restrict__ xh,
                              long long n4) {
    long long i = (long long)blockIdx.x * blockDim.x + threadIdx.x;
    if (i >= n4) return;
    float4 v = ((const float4*)x)[i];
    uint2 o;
    o.x = (uint32)f2bf(v.x) | ((uint32)f2bf(v.y) << 16);
    o.y = (uint32)f2bf(v.z) | ((uint32)f2bf(v.w) << 16);
    ((uint2*)xh)[i] = o;
}

// W1t[n][k], n in [0,128), k in [0,256): k<128 -> W1l[k][n], else W1r[k-128][n]
__global__ void cast_w1_kernel(const float* __restrict__ W1l,
                               const float* __restrict__ W1r,
                               ushort16* __restrict__ W1t) {
    int idx = blockIdx.x * 256 + threadIdx.x;       // 32768
    int n = idx >> 8, k = idx & 255;
    float v = (k < 128) ? W1l[k * 128 + n] : W1r[(k - 128) * 128 + n];
    W1t[n * 256 + k] = f2bf(v);
}

// W2t[n][k], n in [0,128), k in [0,128): n<64 -> W2l[k][n], else W2r[k][n-64]
__global__ void cast_w2_kernel(const float* __restrict__ W2l,
                               const float* __restrict__ W2r,
                               ushort16* __restrict__ W2t) {
    int idx = blockIdx.x * 256 + threadIdx.x;       // 16384
    int n = idx >> 7, k = idx & 127;
    float v = (n < 64) ? W2l[k * 64 + n] : W2r[k * 64 + (n - 64)];
    W2t[n * 128 + k] = f2bf(v);
}

// ---- CSR build -------------------------------------------------------------

__global__ void hist_kernel(const int* __restrict__ dst, int* __restrict__ deg, int E) {
    int e = blockIdx.x * blockDim.x + threadIdx.x;
    if (e < E) atomicAdd(&deg[dst[e]], 1);
}

__global__ void partial_sum_kernel(const int* __restrict__ deg,
                                   int* __restrict__ partials, int N) {
    __shared__ int ws[4];
    int i = blockIdx.x * 256 + threadIdx.x;
    int t = threadIdx.x;
    int v = (i < N) ? deg[i] : 0;
    #pragma unroll
    for (int off = 32; off > 0; off >>= 1) v += __shfl_down(v, off, 64);
    if ((t & 63) == 0) ws[t >> 6] = v;
    __syncthreads();
    if (t == 0) partials[blockIdx.x] = ws[0] + ws[1] + ws[2] + ws[3];
}

__global__ void scan_partials_kernel(int* __restrict__ partials, int nb) {
    __shared__ int buf[256];
    int t = threadIdx.x;
    int v = (t < nb) ? partials[t] : 0;
    buf[t] = v;
    __syncthreads();
    for (int off = 1; off < 256; off <<= 1) {
        int u = (t >= off) ? buf[t - off] : 0;
        __syncthreads();
        buf[t] += u;
        __syncthreads();
    }
    if (t < nb) partials[t] = (t == 0) ? 0 : buf[t - 1];
}

__global__ void scan_final_kernel(const int* __restrict__ deg,
                                  const int* __restrict__ blockoff,
                                  int* __restrict__ rowptr,
                                  int* __restrict__ cursor, int N) {
    __shared__ int buf[256];
    int i = blockIdx.x * 256 + threadIdx.x;
    int t = threadIdx.x;
    int v = (i < N) ? deg[i] : 0;
    buf[t] = v;
    __syncthreads();
    for (int off = 1; off < 256; off <<= 1) {
        int u = (t >= off) ? buf[t - off] : 0;
        __syncthreads();
        buf[t] += u;
        __syncthreads();
    }
    int excl = blockoff[blockIdx.x] + ((t == 0) ? 0 : buf[t - 1]);
    if (i < N) {
        rowptr[i] = excl;
        cursor[i] = excl;
        if (i == N - 1) rowptr[N] = excl + v;
    }
}

__global__ void fill_kernel(const int* __restrict__ src, const int* __restrict__ dst,
                            int* __restrict__ cursor, int* __restrict__ esrc, int E) {
    int e = blockIdx.x * blockDim.x + threadIdx.x;
    if (e < E) {
        int pos = atomicAdd(&cursor[dst[e]], 1);
        esrc[pos] = src[e];
    }
}

// ---- aggregation (bf16 gather, 4-wide MLP) ---------------------------------

// xh rows: 64 uints (128 bf16). lane handles 2 features.
__global__ void agg_mean_x_kernel(const uint32* __restrict__ xh,
                                  const int* __restrict__ rowptr,
                                  const int* __restrict__ esrc,
                                  uint32* __restrict__ meanh, int N) {
    int node = blockIdx.x * 4 + (threadIdx.x >> 6);
    int lane = threadIdx.x & 63;
    if (node >= N) return;
    int s0 = rowptr[node], s1 = rowptr[node + 1];
    if (s0 == s1) { meanh[(size_t)node * 64 + lane] = 0u; return; }
    float ax0 = 0.f, ay0 = 0.f, ax1 = 0.f, ay1 = 0.f;
    float ax2 = 0.f, ay2 = 0.f, ax3 = 0.f, ay3 = 0.f;
    for (int k = s0; k < s1; k += 4) {
        int k1 = k + 1, k2 = k + 2, k3 = k + 3;
        int i0 = esrc[k];
        int i1 = esrc[k1 < s1 ? k1 : k];
        int i2 = esrc[k2 < s1 ? k2 : k];
        int i3 = esrc[k3 < s1 ? k3 : k];
        float m1 = (k1 < s1) ? 1.f : 0.f;
        float m2 = (k2 < s1) ? 1.f : 0.f;
        float m3 = (k3 < s1) ? 1.f : 0.f;
        uint32 v0 = xh[(size_t)i0 * 64 + lane];
        uint32 v1 = xh[(size_t)i1 * 64 + lane];
        uint32 v2 = xh[(size_t)i2 * 64 + lane];
        uint32 v3 = xh[(size_t)i3 * 64 + lane];
        ax0 += __uint_as_float(v0 << 16);      ay0 += __uint_as_float(v0 & 0xFFFF0000u);
        ax1 += __uint_as_float(v1 << 16) * m1; ay1 += __uint_as_float(v1 & 0xFFFF0000u) * m1;
        ax2 += __uint_as_float(v2 << 16) * m2; ay2 += __uint_as_float(v2 & 0xFFFF0000u) * m2;
        ax3 += __uint_as_float(v3 << 16) * m3; ay3 += __uint_as_float(v3 & 0xFFFF0000u) * m3;
    }
    float inv = 1.0f / (float)(s1 - s0);
    float ax = ((ax0 + ax1) + (ax2 + ax3)) * inv;
    float ay = ((ay0 + ay1) + (ay2 + ay3)) * inv;
    meanh[(size_t)node * 64 + lane] = (uint32)f2bf(ax) | ((uint32)f2bf(ay) << 16);
}

// tu rows: 128 bf16; t = cols 0..63, u = cols 64..127. z fp32 [N,64].
__global__ void agg_mean_t_kernel(const ushort16* __restrict__ tu,
                                  const int* __restrict__ rowptr,
                                  const int* __restrict__ esrc,
                                  const float* __restrict__ b2,
                                  float* __restrict__ z, int N) {
    int node = blockIdx.x * 4 + (threadIdx.x >> 6);
    int lane = threadIdx.x & 63;
    if (node >= N) return;
    int s0 = rowptr[node], s1 = rowptr[node + 1];
    float selfu = bf2f(tu[(size_t)node * 128 + 64 + lane]) + b2[lane];
    if (s0 == s1) { z[(size_t)node * 64 + lane] = selfu; return; }
    float a0 = 0.f, a1 = 0.f, a2 = 0.f, a3 = 0.f;
    for (int k = s0; k < s1; k += 4) {
        int k1 = k + 1, k2 = k + 2, k3 = k + 3;
        int i0 = esrc[k];
        int i1 = esrc[k1 < s1 ? k1 : k];
        int i2 = esrc[k2 < s1 ? k2 : k];
        int i3 = esrc[k3 < s1 ? k3 : k];
        float m1 = (k1 < s1) ? 1.f : 0.f;
        float m2 = (k2 < s1) ? 1.f : 0.f;
        float m3 = (k3 < s1) ? 1.f : 0.f;
        a0 += bf2f(tu[(size_t)i0 * 128 + lane]);
        a1 += bf2f(tu[(size_t)i1 * 128 + lane]) * m1;
        a2 += bf2f(tu[(size_t)i2 * 128 + lane]) * m2;
        a3 += bf2f(tu[(size_t)i3 * 128 + lane]) * m3;
    }
    float inv = 1.0f / (float)(s1 - s0);
    z[(size_t)node * 64 + lane] = ((a0 + a1) + (a2 + a3)) * inv + selfu;
}

// ---- MFMA GEMMs ------------------------------------------------------------
// Per-wave 16 rows x 128 cols via 8 MFMA 16x16x32 tiles. No LDS.
// A-frag: A[m=lane&15][k=quad*8+j]; B-frag: Wt[n=lane&15][k=quad*8+j];
// D: row=quad*4+r, col=lane&15  (m89/m91-verified layouts).

__global__ __launch_bounds__(256)
void gemm1_mfma_kernel(const ushort16* __restrict__ meanh,
                       const ushort16* __restrict__ xh,
                       const ushort16* __restrict__ W1t,
                       const float* __restrict__ b1,
                       ushort16* __restrict__ h, int N) {
    int wave = threadIdx.x >> 6;
    int lane = threadIdx.x & 63;
    int m = lane & 15;
    int quad = lane >> 4;
    int row0 = blockIdx.x * 64 + wave * 16;
    int arow = row0 + m; if (arow > N - 1) arow = N - 1;
    f32x4 acc[8];
    #pragma unroll
    for (int c = 0; c < 8; ++c) acc[c] = (f32x4){0.f, 0.f, 0.f, 0.f};
    float bias[8];
    #pragma unroll
    for (int c = 0; c < 8; ++c) bias[c] = b1[c * 16 + m];
    #pragma unroll
    for (int ks = 0; ks < 8; ++ks) {
        int k0 = ks * 32;
        const ushort16* Ab = (ks < 4) ? meanh : xh;
        bf16x8 a = *(const bf16x8*)(Ab + (size_t)arow * 128 + (k0 & 127) + quad * 8);
        #pragma unroll
        for (int c = 0; c < 8; ++c) {
            bf16x8 b = *(const bf16x8*)(W1t + (size_t)(c * 16 + m) * 256 + k0 + quad * 8);
            acc[c] = __builtin_amdgcn_mfma_f32_16x16x32_bf16(a, b, acc[c], 0, 0, 0);
        }
    }
    #pragma unroll
    for (int r = 0; r < 4; ++r) {
        int grow = row0 + quad * 4 + r;
        if (grow >= N) continue;
        #pragma unroll
        for (int c = 0; c < 8; ++c) {
            float v = fmaxf(acc[c][r] + bias[c], 0.f);
            h[(size_t)grow * 128 + c * 16 + m] = f2bf(v);
        }
    }
}

__global__ __launch_bounds__(256)
void gemm2_mfma_kernel(const ushort16* __restrict__ h,
                       const ushort16* __restrict__ W2t,
                       ushort16* __restrict__ tu, int N) {
    int wave = threadIdx.x >> 6;
    int lane = threadIdx.x & 63;
    int m = lane & 15;
    int quad = lane >> 4;
    int row0 = blockIdx.x * 64 + wave * 16;
    int arow = row0 + m; if (arow > N - 1) arow = N - 1;
    f32x4 acc[8];
    #pragma unroll
    for (int c = 0; c < 8; ++c) acc[c] = (f32x4){0.f, 0.f, 0.f, 0.f};
    #pragma unroll
    for (int ks = 0; ks < 4; ++ks) {
        int k0 = ks * 32;
        bf16x8 a = *(const bf16x8*)(h + (size_t)arow * 128 + k0 + quad * 8);
        #pragma unroll
        for (int c = 0; c < 8; ++c) {
            bf16x8 b = *(const bf16x8*)(W2t + (size_t)(c * 16 + m) * 128 + k0 + quad * 8);
            acc[c] = __builtin_amdgcn_mfma_f32_16x16x32_bf16(a, b, acc[c], 0, 0, 0);
        }
    }
    #pragma unroll
    for (int r = 0; r < 4; ++r) {
        int grow = row0 + quad * 4 + r;
        if (grow >= N) continue;
        #pragma unroll
        for (int c = 0; c < 8; ++c) {
            tu[(size_t)grow * 128 + c * 16 + m] = f2bf(acc[c][r]);
        }
    }
}

// ---- link prediction -------------------------------------------------------

__global__ void link_kernel(const float* __restrict__ z,
                            const int* __restrict__ ps,
                            const int* __restrict__ pd,
                            const float* __restrict__ Wlin,
                            const float* __restrict__ blin,
                            float* __restrict__ out, int P) {
    int p = blockIdx.x * 4 + (threadIdx.x >> 6);
    int lane = threadIdx.x & 63;
    if (p >= P) return;
    int a = ps[p];
    int b = pd[p];
    float v = z[(size_t)a * F_OUT + lane] * Wlin[lane]
            + z[(size_t)b * F_OUT + lane] * Wlin[64 + lane];
    #pragma unroll
    for (int off = 32; off > 0; off >>= 1) v += __shfl_down(v, off, 64);
    if (lane == 0) out[p] = 1.0f / (1.0f + expf(-(v + blin[0])));
}

// ---------------------------------------------------------------------------

extern "C" void kernel_launch(void* const* d_in, const int* in_sizes, int n_in,
                              void* d_out, int out_size, void* d_ws, size_t ws_size,
                              hipStream_t stream) {
    const float* x          = (const float*)d_in[0];
    const int*   edge_index = (const int*)d_in[1];
    const int*   edge_pairs = (const int*)d_in[2];
    const float* W1l        = (const float*)d_in[3];
    const float* b1         = (const float*)d_in[4];
    const float* W1r        = (const float*)d_in[5];
    const float* W2l        = (const float*)d_in[6];
    const float* b2         = (const float*)d_in[7];
    const float* W2r        = (const float*)d_in[8];
    const float* Wlin       = (const float*)d_in[9];
    const float* blin       = (const float*)d_in[10];
    float* out = (float*)d_out;

    const int N = in_sizes[0] / 128;       // 50000
    const int E = in_sizes[1] / 2;         // 800000
    const int P = in_sizes[2] / 2;         // 200000

    const int* src = edge_index;
    const int* dst = edge_index + E;
    const int* ps  = edge_pairs;
    const int* pd  = edge_pairs + P;

    // workspace layout (bytes all 16-aligned)
    ushort16* xh    = (ushort16*)d_ws;                 // N*128 bf16
    ushort16* meanh = xh + (size_t)N * 128;            // N*128 bf16, reused as z (N*64 f32)
    ushort16* h     = meanh + (size_t)N * 128;         // N*128 bf16
    ushort16* tu    = h + (size_t)N * 128;             // N*128 bf16
    ushort16* W1t   = tu + (size_t)N * 128;            // 128*256 bf16
    ushort16* W2t   = W1t + 128 * 256;                 // 128*128 bf16
    int* deg      = (int*)(W2t + 128 * 128);
    int* rowptr   = deg + N;
    int* cursor   = rowptr + N + 1;
    int* esrc     = cursor + N;
    int* partials = esrc + E;
    float* z = (float*)meanh;                          // N*64 f32 (same bytes as meanh)

    const int scan_blocks = (N + 255) / 256;           // 196

    // casts
    long long n4 = (long long)N * 128 / 4;
    cast_x_kernel<<<(int)((n4 + 255) / 256), 256, 0, stream>>>(x, (uint32*)xh, n4);
    cast_w1_kernel<<<128, 256, 0, stream>>>(W1l, W1r, W1t);
    cast_w2_kernel<<<64, 256, 0, stream>>>(W2l, W2r, W2t);

    // CSR build
    hipMemsetAsync(deg, 0, (size_t)N * sizeof(int), stream);
    hist_kernel<<<(E + 255) / 256, 256, 0, stream>>>(dst, deg, E);
    partial_sum_kernel<<<scan_blocks, 256, 0, stream>>>(deg, partials, N);
    scan_partials_kernel<<<1, 256, 0, stream>>>(partials, scan_blocks);
    scan_final_kernel<<<scan_blocks, 256, 0, stream>>>(deg, partials, rowptr, cursor, N);
    fill_kernel<<<(E + 255) / 256, 256, 0, stream>>>(src, dst, cursor, esrc, E);

    // layer 1
    agg_mean_x_kernel<<<(N + 3) / 4, 256, 0, stream>>>((const uint32*)xh, rowptr, esrc,
                                                       (uint32*)meanh, N);
    gemm1_mfma_kernel<<<(N + 63) / 64, 256, 0, stream>>>(meanh, xh, W1t, b1, h, N);

    // layer 2 (transform first, aggregate 64-dim t)
    gemm2_mfma_kernel<<<(N + 63) / 64, 256, 0, stream>>>(h, W2t, tu, N);
    agg_mean_t_kernel<<<(N + 3) / 4, 256, 0, stream>>>(tu, rowptr, esrc, b2, z, N);

    // link prediction
    link_kernel<<<(P + 3) / 4, 256, 0, stream>>>(z, ps, pd, Wlin, blin, out, P);
}

// Round 7
// 299.605 us; speedup vs baseline: 3.8039x; 1.1517x over previous
//
#include <hip/hip_runtime.h>
#include <math.h>

// ---------------------------------------------------------------------------
// 2-layer GraphSAGE (mean aggr) + link predictor. bf16 MFMA version.
//
//   prep: cast x->bf16, weights->Wt[n][k] bf16, hist(deg)   [one fused launch]
//   3-phase scan -> fill(esrc ushort, 4-wide)               [CSR build]
//   agg1: meanh = mean_{j} xh_j                     (bf16 gather, 8-wide MLP)
//   GEMM1: h = relu([meanh|xh] @ W1 + b1)           (MFMA 16x16x32 bf16)
//   GEMM2: tu = h @ [W2l|W2r]                       (MFMA 16x16x32 bf16)
//   agg2+linkprep: z = mean_t + u + b2; za=z.Wlin[:64], zb=z.Wlin[64:]
//   link: sigmoid(za[ps]+zb[pd]+blin)               (2x 4B gather per pair)
// ---------------------------------------------------------------------------

typedef __attribute__((ext_vector_type(8))) short bf16x8;
typedef __attribute__((ext_vector_type(4))) float f32x4;
typedef unsigned int uint32;
typedef unsigned short ushort16;

__device__ __forceinline__ ushort16 f2bf(float f) {
    uint32 u = __float_as_uint(f);
    uint32 r = u + 0x7FFFu + ((u >> 16) & 1u);   // round-to-nearest-even
    return (ushort16)(r >> 16);
}
__device__ __forceinline__ float bf2f(ushort16 u) {
    return __uint_as_float(((uint32)u) << 16);
}

// ---- fused prep: cast_x | cast_w1 | cast_w2 | hist (block-range split) -----

__global__ __launch_bounds__(256)
void prep_kernel(const float* __restrict__ x, uint32* __restrict__ xh, long long n4,
                 const float* __restrict__ W1l, const float* __restrict__ W1r,
                 ushort16* __restrict__ W1t,
                 const float* __restrict__ W2l, const float* __restrict__ W2r,
                 ushort16* __restrict__ W2t,
                 const int* __restrict__ dst, int* __restrict__ deg, int E,
                 int nbx, int nbw1, int nbw2, int histT) {
    int b = blockIdx.x;
    int t = threadIdx.x;
    if (b < nbx) {
        long long i = (long long)b * 256 + t;
        if (i < n4) {
            float4 v = ((const float4*)x)[i];
            uint2 o;
            o.x = (uint32)f2bf(v.x) | ((uint32)f2bf(v.y) << 16);
            o.y = (uint32)f2bf(v.z) | ((uint32)f2bf(v.w) << 16);
            ((uint2*)xh)[i] = o;
        }
    } else if (b < nbx + nbw1) {
        int idx = (b - nbx) * 256 + t;            // 32768: W1t[n][k], k<128->W1l
        int n = idx >> 8, k = idx & 255;
        float v = (k < 128) ? W1l[k * 128 + n] : W1r[(k - 128) * 128 + n];
        W1t[n * 256 + k] = f2bf(v);
    } else if (b < nbx + nbw1 + nbw2) {
        int idx = (b - nbx - nbw1) * 256 + t;     // 16384: W2t[n][k], n<64->W2l
        int n = idx >> 7, k = idx & 127;
        float v = (n < 64) ? W2l[k * 64 + n] : W2r[k * 64 + (n - 64)];
        W2t[n * 128 + k] = f2bf(v);
    } else {
        int base = (b - nbx - nbw1 - nbw2) * 256 + t;
        #pragma unroll
        for (int j = 0; j < 4; ++j) {
            int e = base + j * histT;
            if (e < E) atomicAdd(&deg[dst[e]], 1);
        }
    }
}

// ---- CSR scan + fill -------------------------------------------------------

__global__ void partial_sum_kernel(const int* __restrict__ deg,
                                   int* __restrict__ partials, int N) {
    __shared__ int ws[4];
    int i = blockIdx.x * 256 + threadIdx.x;
    int t = threadIdx.x;
    int v = (i < N) ? deg[i] : 0;
    #pragma unroll
    for (int off = 32; off > 0; off >>= 1) v += __shfl_down(v, off, 64);
    if ((t & 63) == 0) ws[t >> 6] = v;
    __syncthreads();
    if (t == 0) partials[blockIdx.x] = ws[0] + ws[1] + ws[2] + ws[3];
}

__global__ void scan_partials_kernel(int* __restrict__ partials, int nb) {
    __shared__ int buf[256];
    int t = threadIdx.x;
    int v = (t < nb) ? partials[t] : 0;
    buf[t] = v;
    __syncthreads();
    for (int off = 1; off < 256; off <<= 1) {
        int u = (t >= off) ? buf[t - off] : 0;
        __syncthreads();
        buf[t] += u;
        __syncthreads();
    }
    if (t < nb) partials[t] = (t == 0) ? 0 : buf[t - 1];
}

__global__ void scan_final_kernel(const int* __restrict__ deg,
                                  const int* __restrict__ blockoff,
                                  int* __restrict__ rowptr,
                                  int* __restrict__ cursor, int N) {
    __shared__ int buf[256];
    int i = blockIdx.x * 256 + threadIdx.x;
    int t = threadIdx.x;
    int v = (i < N) ? deg[i] : 0;
    buf[t] = v;
    __syncthreads();
    for (int off = 1; off < 256; off <<= 1) {
        int u = (t >= off) ? buf[t - off] : 0;
        __syncthreads();
        buf[t] += u;
        __syncthreads();
    }
    int excl = blockoff[blockIdx.x] + ((t == 0) ? 0 : buf[t - 1]);
    if (i < N) {
        rowptr[i] = excl;
        cursor[i] = excl;
        if (i == N - 1) rowptr[N] = excl + v;
    }
}

__global__ void fill_kernel(const int* __restrict__ src, const int* __restrict__ dst,
                            int* __restrict__ cursor, ushort16* __restrict__ esrc,
                            int E, int T) {
    int base = blockIdx.x * blockDim.x + threadIdx.x;
    #pragma unroll
    for (int j = 0; j < 4; ++j) {
        int e = base + j * T;
        if (e < E) {
            int pos = atomicAdd(&cursor[dst[e]], 1);
            esrc[pos] = (ushort16)src[e];
        }
    }
}

// ---- aggregation (bf16 gather, 8-wide MLP) ---------------------------------

// xh rows: 64 uints (128 bf16); lane handles 2 features.
__global__ void agg_mean_x_kernel(const uint32* __restrict__ xh,
                                  const int* __restrict__ rowptr,
                                  const ushort16* __restrict__ esrc,
                                  uint32* __restrict__ meanh, int N) {
    int node = blockIdx.x * 4 + (threadIdx.x >> 6);
    int lane = threadIdx.x & 63;
    if (node >= N) return;
    int s0 = rowptr[node], s1 = rowptr[node + 1];
    if (s0 == s1) { meanh[(size_t)node * 64 + lane] = 0u; return; }
    float ax[8] = {}, ay[8] = {};
    for (int k = s0; k < s1; k += 8) {
        int idx[8]; float msk[8];
        #pragma unroll
        for (int j = 0; j < 8; ++j) {
            int kj = k + j;
            idx[j] = esrc[kj < s1 ? kj : k];
            msk[j] = (kj < s1) ? 1.f : 0.f;
        }
        #pragma unroll
        for (int j = 0; j < 8; ++j) {
            uint32 v = xh[(size_t)idx[j] * 64 + lane];
            ax[j] += __uint_as_float(v << 16) * msk[j];
            ay[j] += __uint_as_float(v & 0xFFFF0000u) * msk[j];
        }
    }
    float inv = 1.0f / (float)(s1 - s0);
    float sx = ((ax[0] + ax[1]) + (ax[2] + ax[3])) + ((ax[4] + ax[5]) + (ax[6] + ax[7]));
    float sy = ((ay[0] + ay[1]) + (ay[2] + ay[3])) + ((ay[4] + ay[5]) + (ay[6] + ay[7]));
    meanh[(size_t)node * 64 + lane] = (uint32)f2bf(sx * inv) | ((uint32)f2bf(sy * inv) << 16);
}

// z = mean_t + u + b2, then fold link weights per node:
// za[i] = sum_l z[i][l]*Wlin[l], zb[i] = sum_l z[i][l]*Wlin[64+l]
__global__ void agg_link_prep_kernel(const ushort16* __restrict__ tu,
                                     const int* __restrict__ rowptr,
                                     const ushort16* __restrict__ esrc,
                                     const float* __restrict__ b2,
                                     const float* __restrict__ Wlin,
                                     float* __restrict__ za, float* __restrict__ zb,
                                     int N) {
    int node = blockIdx.x * 4 + (threadIdx.x >> 6);
    int lane = threadIdx.x & 63;
    if (node >= N) return;
    int s0 = rowptr[node], s1 = rowptr[node + 1];
    float zl = bf2f(tu[(size_t)node * 128 + 64 + lane]) + b2[lane];   // self term
    if (s0 < s1) {
        float a[8] = {};
        for (int k = s0; k < s1; k += 8) {
            int idx[8]; float msk[8];
            #pragma unroll
            for (int j = 0; j < 8; ++j) {
                int kj = k + j;
                idx[j] = esrc[kj < s1 ? kj : k];
                msk[j] = (kj < s1) ? 1.f : 0.f;
            }
            #pragma unroll
            for (int j = 0; j < 8; ++j)
                a[j] += bf2f(tu[(size_t)idx[j] * 128 + lane]) * msk[j];
        }
        float inv = 1.0f / (float)(s1 - s0);
        zl += (((a[0] + a[1]) + (a[2] + a[3])) + ((a[4] + a[5]) + (a[6] + a[7]))) * inv;
    }
    float va = zl * Wlin[lane];
    float vb = zl * Wlin[64 + lane];
    #pragma unroll
    for (int off = 32; off > 0; off >>= 1) {
        va += __shfl_down(va, off, 64);
        vb += __shfl_down(vb, off, 64);
    }
    if (lane == 0) { za[node] = va; zb[node] = vb; }
}

// ---- MFMA GEMMs ------------------------------------------------------------
// Per-wave 16 rows x 128 cols via 8 MFMA 16x16x32 tiles. No LDS.
// A-frag: A[m=lane&15][k=quad*8+j]; B-frag: Wt[n=lane&15][k=quad*8+j];
// D: row=quad*4+r, col=lane&15  (m89/m91-verified layouts).

__global__ __launch_bounds__(256)
void gemm1_mfma_kernel(const ushort16* __restrict__ meanh,
                       const ushort16* __restrict__ xh,
                       const ushort16* __restrict__ W1t,
                       const float* __restrict__ b1,
                       ushort16* __restrict__ h, int N) {
    int wave = threadIdx.x >> 6;
    int lane = threadIdx.x & 63;
    int m = lane & 15;
    int quad = lane >> 4;
    int row0 = blockIdx.x * 64 + wave * 16;
    int arow = row0 + m; if (arow > N - 1) arow = N - 1;
    f32x4 acc[8];
    #pragma unroll
    for (int c = 0; c < 8; ++c) acc[c] = (f32x4){0.f, 0.f, 0.f, 0.f};
    float bias[8];
    #pragma unroll
    for (int c = 0; c < 8; ++c) bias[c] = b1[c * 16 + m];
    #pragma unroll
    for (int ks = 0; ks < 8; ++ks) {
        int k0 = ks * 32;
        const ushort16* Ab = (ks < 4) ? meanh : xh;
        bf16x8 a = *(const bf16x8*)(Ab + (size_t)arow * 128 + (k0 & 127) + quad * 8);
        #pragma unroll
        for (int c = 0; c < 8; ++c) {
            bf16x8 b = *(const bf16x8*)(W1t + (size_t)(c * 16 + m) * 256 + k0 + quad * 8);
            acc[c] = __builtin_amdgcn_mfma_f32_16x16x32_bf16(a, b, acc[c], 0, 0, 0);
        }
    }
    #pragma unroll
    for (int r = 0; r < 4; ++r) {
        int grow = row0 + quad * 4 + r;
        if (grow >= N) continue;
        #pragma unroll
        for (int c = 0; c < 8; ++c) {
            float v = fmaxf(acc[c][r] + bias[c], 0.f);
            h[(size_t)grow * 128 + c * 16 + m] = f2bf(v);
        }
    }
}

__global__ __launch_bounds__(256)
void gemm2_mfma_kernel(const ushort16* __restrict__ h,
                       const ushort16* __restrict__ W2t,
                       ushort16* __restrict__ tu, int N) {
    int wave = threadIdx.x >> 6;
    int lane = threadIdx.x & 63;
    int m = lane & 15;
    int quad = lane >> 4;
    int row0 = blockIdx.x * 64 + wave * 16;
    int arow = row0 + m; if (arow > N - 1) arow = N - 1;
    f32x4 acc[8];
    #pragma unroll
    for (int c = 0; c < 8; ++c) acc[c] = (f32x4){0.f, 0.f, 0.f, 0.f};
    #pragma unroll
    for (int ks = 0; ks < 4; ++ks) {
        int k0 = ks * 32;
        bf16x8 a = *(const bf16x8*)(h + (size_t)arow * 128 + k0 + quad * 8);
        #pragma unroll
        for (int c = 0; c < 8; ++c) {
            bf16x8 b = *(const bf16x8*)(W2t + (size_t)(c * 16 + m) * 128 + k0 + quad * 8);
            acc[c] = __builtin_amdgcn_mfma_f32_16x16x32_bf16(a, b, acc[c], 0, 0, 0);
        }
    }
    #pragma unroll
    for (int r = 0; r < 4; ++r) {
        int grow = row0 + quad * 4 + r;
        if (grow >= N) continue;
        #pragma unroll
        for (int c = 0; c < 8; ++c) {
            tu[(size_t)grow * 128 + c * 16 + m] = f2bf(acc[c][r]);
        }
    }
}

// ---- link prediction: out[p] = sigmoid(za[ps] + zb[pd] + blin) -------------

__global__ void link_kernel(const float* __restrict__ za, const float* __restrict__ zb,
                            const int* __restrict__ ps, const int* __restrict__ pd,
                            const float* __restrict__ blin,
                            float* __restrict__ out, int P) {
    int p = blockIdx.x * blockDim.x + threadIdx.x;
    if (p >= P) return;
    float logit = za[ps[p]] + zb[pd[p]] + blin[0];
    out[p] = 1.0f / (1.0f + expf(-logit));
}

// ---------------------------------------------------------------------------

extern "C" void kernel_launch(void* const* d_in, const int* in_sizes, int n_in,
                              void* d_out, int out_size, void* d_ws, size_t ws_size,
                              hipStream_t stream) {
    const float* x          = (const float*)d_in[0];
    const int*   edge_index = (const int*)d_in[1];
    const int*   edge_pairs = (const int*)d_in[2];
    const float* W1l        = (const float*)d_in[3];
    const float* b1         = (const float*)d_in[4];
    const float* W1r        = (const float*)d_in[5];
    const float* W2l        = (const float*)d_in[6];
    const float* b2         = (const float*)d_in[7];
    const float* W2r        = (const float*)d_in[8];
    const float* Wlin       = (const float*)d_in[9];
    const float* blin       = (const float*)d_in[10];
    float* out = (float*)d_out;

    const int N = in_sizes[0] / 128;       // 50000
    const int E = in_sizes[1] / 2;         // 800000
    const int P = in_sizes[2] / 2;         // 200000

    const int* src = edge_index;
    const int* dst = edge_index + E;
    const int* ps  = edge_pairs;
    const int* pd  = edge_pairs + P;

    // workspace layout
    ushort16* xh    = (ushort16*)d_ws;                 // N*128 bf16
    ushort16* meanh = xh + (size_t)N * 128;            // N*128 bf16
    ushort16* h     = meanh + (size_t)N * 128;         // N*128 bf16
    ushort16* tu    = h + (size_t)N * 128;             // N*128 bf16
    ushort16* W1t   = tu + (size_t)N * 128;            // 128*256 bf16
    ushort16* W2t   = W1t + 128 * 256;                 // 128*128 bf16
    float* za     = (float*)(W2t + 128 * 128);         // N f32
    float* zb     = za + N;                            // N f32
    int* deg      = (int*)(zb + N);
    int* rowptr   = deg + N;
    int* cursor   = rowptr + N + 1;
    ushort16* esrc = (ushort16*)(cursor + N);          // E ushort
    int* partials = (int*)(esrc + E);

    const int scan_blocks = (N + 255) / 256;           // 196
    const long long n4 = (long long)N * 128 / 4;       // 1.6M
    const int nbx  = (int)((n4 + 255) / 256);          // 6250
    const int nbw1 = 128, nbw2 = 64;
    const int nbh  = ((E + 3) / 4 + 255) / 256;        // 782
    const int histT = nbh * 256;                       // 200192

    hipMemsetAsync(deg, 0, (size_t)N * sizeof(int), stream);

    // fused prep: cast x, cast+transpose weights, degree histogram
    prep_kernel<<<nbx + nbw1 + nbw2 + nbh, 256, 0, stream>>>(
        x, (uint32*)xh, n4, W1l, W1r, W1t, W2l, W2r, W2t,
        dst, deg, E, nbx, nbw1, nbw2, histT);

    // CSR scan + fill
    partial_sum_kernel<<<scan_blocks, 256, 0, stream>>>(deg, partials, N);
    scan_partials_kernel<<<1, 256, 0, stream>>>(partials, scan_blocks);
    scan_final_kernel<<<scan_blocks, 256, 0, stream>>>(deg, partials, rowptr, cursor, N);
    fill_kernel<<<nbh, 256, 0, stream>>>(src, dst, cursor, esrc, E, histT);

    // layer 1
    agg_mean_x_kernel<<<(N + 3) / 4, 256, 0, stream>>>((const uint32*)xh, rowptr, esrc,
                                                       (uint32*)meanh, N);
    gemm1_mfma_kernel<<<(N + 63) / 64, 256, 0, stream>>>(meanh, xh, W1t, b1, h, N);

    // layer 2 (transform first, aggregate 64-dim t, fold link weights)
    gemm2_mfma_kernel<<<(N + 63) / 64, 256, 0, stream>>>(h, W2t, tu, N);
    agg_link_prep_kernel<<<(N + 3) / 4, 256, 0, stream>>>(tu, rowptr, esrc, b2, Wlin,
                                                          za, zb, N);

    // link prediction
    link_kernel<<<(P + 255) / 256, 256, 0, stream>>>(za, zb, ps, pd, blin, out, P);
}

// Round 8
// 279.056 us; speedup vs baseline: 4.0840x; 1.0736x over previous
//
#include <hip/hip_runtime.h>
#include <math.h>

// ---------------------------------------------------------------------------
// 2-layer GraphSAGE (mean aggr) + link predictor. bf16 MFMA + folded layer 2.
//
//   prep: cast x->bf16, W1->W1t[n][k] bf16, fold W2/Wlin/b2, hist(deg)
//   3-phase scan -> fill(esrc ushort, 4-wide)               [CSR build]
//   agg1: meanh = mean_{j} xh_j                     (bf16 gather, 8-wide MLP)
//   GEMM1: h = relu([meanh|xh] @ W1 + b1)           (MFMA 16x16x32 bf16)
//   GEMV:  pa,pc,qb,qd = h . {va,vc,vbp,vd}         (wave per node, 4 dots)
//   agg2:  za = mean_j pa + qb + ca; zb = mean_j pc + qd + cb  (8B/edge gather)
//   link:  sigmoid(za[ps]+zb[pd]+blin)
//
// Layer-2 algebra: z = mean@W2l + b2 + h@W2r; logits use only z.Wa, z.Wb
//   (Wa=Wlin[:64], Wb=Wlin[64:]) -> fold va=W2l@Wa, vc=W2l@Wb, vbp=W2r@Wa,
//   vd=W2r@Wb, ca=b2.Wa, cb=b2.Wb. GEMM2 eliminated.
// ---------------------------------------------------------------------------

typedef __attribute__((ext_vector_type(8))) short bf16x8;
typedef __attribute__((ext_vector_type(4))) float f32x4;
typedef unsigned int uint32;
typedef unsigned short ushort16;

__device__ __forceinline__ ushort16 f2bf(float f) {
    uint32 u = __float_as_uint(f);
    uint32 r = u + 0x7FFFu + ((u >> 16) & 1u);   // round-to-nearest-even
    return (ushort16)(r >> 16);
}
__device__ __forceinline__ float bf2f(ushort16 u) {
    return __uint_as_float(((uint32)u) << 16);
}

// ---- fused prep: cast_x | cast_w1 | fold_w2 | hist (block-range split) -----

__global__ __launch_bounds__(256)
void prep_kernel(const float* __restrict__ x, uint32* __restrict__ xh, long long n4,
                 const float* __restrict__ W1l, const float* __restrict__ W1r,
                 ushort16* __restrict__ W1t,
                 const float* __restrict__ W2l, const float* __restrict__ W2r,
                 const float* __restrict__ Wlin, const float* __restrict__ b2,
                 float* __restrict__ fw, float* __restrict__ fc,
                 const int* __restrict__ dst, int* __restrict__ deg, int E,
                 int nbx, int nbw1, int histT) {
    int b = blockIdx.x;
    int t = threadIdx.x;
    if (b < nbx) {
        long long i = (long long)b * 256 + t;
        if (i < n4) {
            float4 v = ((const float4*)x)[i];
            uint2 o;
            o.x = (uint32)f2bf(v.x) | ((uint32)f2bf(v.y) << 16);
            o.y = (uint32)f2bf(v.z) | ((uint32)f2bf(v.w) << 16);
            ((uint2*)xh)[i] = o;
        }
    } else if (b < nbx + nbw1) {
        int idx = (b - nbx) * 256 + t;            // 32768: W1t[n][k], k<128->W1l
        int n = idx >> 8, k = idx & 255;
        float v = (k < 128) ? W1l[k * 128 + n] : W1r[(k - 128) * 128 + n];
        W1t[n * 256 + k] = f2bf(v);
    } else if (b == nbx + nbw1) {
        // fold layer-2 weights with link weights
        if (t < 128) {
            float a = 0.f, c = 0.f;
            for (int l = 0; l < 64; ++l) {
                float w = W2l[t * 64 + l];
                a += w * Wlin[l];
                c += w * Wlin[64 + l];
            }
            fw[t] = a; fw[128 + t] = c;
        } else {
            int k = t - 128;
            float a = 0.f, c = 0.f;
            for (int l = 0; l < 64; ++l) {
                float w = W2r[k * 64 + l];
                a += w * Wlin[l];
                c += w * Wlin[64 + l];
            }
            fw[256 + k] = a; fw[384 + k] = c;
        }
        if (t == 0) { float s = 0.f; for (int l = 0; l < 64; ++l) s += b2[l] * Wlin[l];      fc[0] = s; }
        if (t == 1) { float s = 0.f; for (int l = 0; l < 64; ++l) s += b2[l] * Wlin[64 + l]; fc[1] = s; }
    } else {
        int base = (b - nbx - nbw1 - 1) * 256 + t;
        #pragma unroll
        for (int j = 0; j < 4; ++j) {
            int e = base + j * histT;
            if (e < E) atomicAdd(&deg[dst[e]], 1);
        }
    }
}

// ---- CSR scan + fill -------------------------------------------------------

__global__ void partial_sum_kernel(const int* __restrict__ deg,
                                   int* __restrict__ partials, int N) {
    __shared__ int ws[4];
    int i = blockIdx.x * 256 + threadIdx.x;
    int t = threadIdx.x;
    int v = (i < N) ? deg[i] : 0;
    #pragma unroll
    for (int off = 32; off > 0; off >>= 1) v += __shfl_down(v, off, 64);
    if ((t & 63) == 0) ws[t >> 6] = v;
    __syncthreads();
    if (t == 0) partials[blockIdx.x] = ws[0] + ws[1] + ws[2] + ws[3];
}

__global__ void scan_partials_kernel(int* __restrict__ partials, int nb) {
    __shared__ int buf[256];
    int t = threadIdx.x;
    int v = (t < nb) ? partials[t] : 0;
    buf[t] = v;
    __syncthreads();
    for (int off = 1; off < 256; off <<= 1) {
        int u = (t >= off) ? buf[t - off] : 0;
        __syncthreads();
        buf[t] += u;
        __syncthreads();
    }
    if (t < nb) partials[t] = (t == 0) ? 0 : buf[t - 1];
}

__global__ void scan_final_kernel(const int* __restrict__ deg,
                                  const int* __restrict__ blockoff,
                                  int* __restrict__ rowptr,
                                  int* __restrict__ cursor, int N) {
    __shared__ int buf[256];
    int i = blockIdx.x * 256 + threadIdx.x;
    int t = threadIdx.x;
    int v = (i < N) ? deg[i] : 0;
    buf[t] = v;
    __syncthreads();
    for (int off = 1; off < 256; off <<= 1) {
        int u = (t >= off) ? buf[t - off] : 0;
        __syncthreads();
        buf[t] += u;
        __syncthreads();
    }
    int excl = blockoff[blockIdx.x] + ((t == 0) ? 0 : buf[t - 1]);
    if (i < N) {
        rowptr[i] = excl;
        cursor[i] = excl;
        if (i == N - 1) rowptr[N] = excl + v;
    }
}

__global__ void fill_kernel(const int* __restrict__ src, const int* __restrict__ dst,
                            int* __restrict__ cursor, ushort16* __restrict__ esrc,
                            int E, int T) {
    int base = blockIdx.x * blockDim.x + threadIdx.x;
    #pragma unroll
    for (int j = 0; j < 4; ++j) {
        int e = base + j * T;
        if (e < E) {
            int pos = atomicAdd(&cursor[dst[e]], 1);
            esrc[pos] = (ushort16)src[e];
        }
    }
}

// ---- aggregation (bf16 gather, 8-wide MLP) ---------------------------------

__global__ void agg_mean_x_kernel(const uint32* __restrict__ xh,
                                  const int* __restrict__ rowptr,
                                  const ushort16* __restrict__ esrc,
                                  uint32* __restrict__ meanh, int N) {
    int node = blockIdx.x * 4 + (threadIdx.x >> 6);
    int lane = threadIdx.x & 63;
    if (node >= N) return;
    int s0 = rowptr[node], s1 = rowptr[node + 1];
    if (s0 == s1) { meanh[(size_t)node * 64 + lane] = 0u; return; }
    float ax[8] = {}, ay[8] = {};
    for (int k = s0; k < s1; k += 8) {
        int idx[8]; float msk[8];
        #pragma unroll
        for (int j = 0; j < 8; ++j) {
            int kj = k + j;
            idx[j] = esrc[kj < s1 ? kj : k];
            msk[j] = (kj < s1) ? 1.f : 0.f;
        }
        #pragma unroll
        for (int j = 0; j < 8; ++j) {
            uint32 v = xh[(size_t)idx[j] * 64 + lane];
            ax[j] += __uint_as_float(v << 16) * msk[j];
            ay[j] += __uint_as_float(v & 0xFFFF0000u) * msk[j];
        }
    }
    float inv = 1.0f / (float)(s1 - s0);
    float sx = ((ax[0] + ax[1]) + (ax[2] + ax[3])) + ((ax[4] + ax[5]) + (ax[6] + ax[7]));
    float sy = ((ay[0] + ay[1]) + (ay[2] + ay[3])) + ((ay[4] + ay[5]) + (ay[6] + ay[7]));
    meanh[(size_t)node * 64 + lane] = (uint32)f2bf(sx * inv) | ((uint32)f2bf(sy * inv) << 16);
}

// ---- MFMA GEMM 1 -----------------------------------------------------------
// Per-wave 16 rows x 128 cols via 8 MFMA 16x16x32 tiles. No LDS.
// A-frag: A[m=lane&15][k=quad*8+j]; B-frag: Wt[n=lane&15][k=quad*8+j];
// D: row=quad*4+r, col=lane&15  (m89/m91-verified layouts).

__global__ __launch_bounds__(256)
void gemm1_mfma_kernel(const ushort16* __restrict__ meanh,
                       const ushort16* __restrict__ xh,
                       const ushort16* __restrict__ W1t,
                       const float* __restrict__ b1,
                       ushort16* __restrict__ h, int N) {
    int wave = threadIdx.x >> 6;
    int lane = threadIdx.x & 63;
    int m = lane & 15;
    int quad = lane >> 4;
    int row0 = blockIdx.x * 64 + wave * 16;
    int arow = row0 + m; if (arow > N - 1) arow = N - 1;
    f32x4 acc[8];
    #pragma unroll
    for (int c = 0; c < 8; ++c) acc[c] = (f32x4){0.f, 0.f, 0.f, 0.f};
    float bias[8];
    #pragma unroll
    for (int c = 0; c < 8; ++c) bias[c] = b1[c * 16 + m];
    #pragma unroll
    for (int ks = 0; ks < 8; ++ks) {
        int k0 = ks * 32;
        const ushort16* Ab = (ks < 4) ? meanh : xh;
        bf16x8 a = *(const bf16x8*)(Ab + (size_t)arow * 128 + (k0 & 127) + quad * 8);
        #pragma unroll
        for (int c = 0; c < 8; ++c) {
            bf16x8 b = *(const bf16x8*)(W1t + (size_t)(c * 16 + m) * 256 + k0 + quad * 8);
            acc[c] = __builtin_amdgcn_mfma_f32_16x16x32_bf16(a, b, acc[c], 0, 0, 0);
        }
    }
    #pragma unroll
    for (int r = 0; r < 4; ++r) {
        int grow = row0 + quad * 4 + r;
        if (grow >= N) continue;
        #pragma unroll
        for (int c = 0; c < 8; ++c) {
            float v = fmaxf(acc[c][r] + bias[c], 0.f);
            h[(size_t)grow * 128 + c * 16 + m] = f2bf(v);
        }
    }
}

// ---- GEMV: 4 folded dots per node (wave per node) --------------------------

__global__ __launch_bounds__(256)
void gemv_kernel(const uint32* __restrict__ h, const float* __restrict__ fw,
                 float2* __restrict__ pab, float2* __restrict__ quv, int N) {
    int node = blockIdx.x * 4 + (threadIdx.x >> 6);
    int l = threadIdx.x & 63;
    if (node >= N) return;
    uint32 v = h[(size_t)node * 64 + l];
    float x0 = __uint_as_float(v << 16);
    float x1 = __uint_as_float(v & 0xFFFF0000u);
    float pa = x0 * fw[2 * l]       + x1 * fw[2 * l + 1];
    float pc = x0 * fw[128 + 2 * l] + x1 * fw[128 + 2 * l + 1];
    float qb = x0 * fw[256 + 2 * l] + x1 * fw[256 + 2 * l + 1];
    float qd = x0 * fw[384 + 2 * l] + x1 * fw[384 + 2 * l + 1];
    #pragma unroll
    for (int off = 1; off < 64; off <<= 1) {
        pa += __shfl_xor(pa, off, 64);
        pc += __shfl_xor(pc, off, 64);
        qb += __shfl_xor(qb, off, 64);
        qd += __shfl_xor(qd, off, 64);
    }
    if (l == 0) {
        pab[node] = make_float2(pa, pc);
        quv[node] = make_float2(qb, qd);
    }
}

// ---- layer-2 aggregation on scalars (thread per node, 4-wide MLP) ----------

__global__ void agg_link_kernel(const float2* __restrict__ pab,
                                const float2* __restrict__ quv,
                                const int* __restrict__ rowptr,
                                const ushort16* __restrict__ esrc,
                                const float* __restrict__ fc,
                                float* __restrict__ za, float* __restrict__ zb, int N) {
    int i = blockIdx.x * blockDim.x + threadIdx.x;
    if (i >= N) return;
    int s0 = rowptr[i], s1 = rowptr[i + 1];
    float a0 = 0.f, a1 = 0.f, a2 = 0.f, a3 = 0.f;
    float c0 = 0.f, c1 = 0.f, c2 = 0.f, c3 = 0.f;
    for (int k = s0; k < s1; k += 4) {
        int k1 = k + 1, k2 = k + 2, k3 = k + 3;
        int i0 = esrc[k];
        int i1 = esrc[k1 < s1 ? k1 : k];
        int i2 = esrc[k2 < s1 ? k2 : k];
        int i3 = esrc[k3 < s1 ? k3 : k];
        float m1 = (k1 < s1) ? 1.f : 0.f;
        float m2 = (k2 < s1) ? 1.f : 0.f;
        float m3 = (k3 < s1) ? 1.f : 0.f;
        float2 p0 = pab[i0], p1 = pab[i1], p2 = pab[i2], p3 = pab[i3];
        a0 += p0.x;      c0 += p0.y;
        a1 += p1.x * m1; c1 += p1.y * m1;
        a2 += p2.x * m2; c2 += p2.y * m2;
        a3 += p3.x * m3; c3 += p3.y * m3;
    }
    float spa = (a0 + a1) + (a2 + a3);
    float spc = (c0 + c1) + (c2 + c3);
    float inv = (s1 > s0) ? 1.0f / (float)(s1 - s0) : 0.f;
    float2 q = quv[i];
    za[i] = spa * inv + q.x + fc[0];
    zb[i] = spc * inv + q.y + fc[1];
}

// ---- link prediction: out[p] = sigmoid(za[ps] + zb[pd] + blin) -------------

__global__ void link_kernel(const float* __restrict__ za, const float* __restrict__ zb,
                            const int* __restrict__ ps, const int* __restrict__ pd,
                            const float* __restrict__ blin,
                            float* __restrict__ out, int P) {
    int p = blockIdx.x * blockDim.x + threadIdx.x;
    if (p >= P) return;
    float logit = za[ps[p]] + zb[pd[p]] + blin[0];
    out[p] = 1.0f / (1.0f + expf(-logit));
}

// ---------------------------------------------------------------------------

extern "C" void kernel_launch(void* const* d_in, const int* in_sizes, int n_in,
                              void* d_out, int out_size, void* d_ws, size_t ws_size,
                              hipStream_t stream) {
    const float* x          = (const float*)d_in[0];
    const int*   edge_index = (const int*)d_in[1];
    const int*   edge_pairs = (const int*)d_in[2];
    const float* W1l        = (const float*)d_in[3];
    const float* b1         = (const float*)d_in[4];
    const float* W1r        = (const float*)d_in[5];
    const float* W2l        = (const float*)d_in[6];
    const float* b2         = (const float*)d_in[7];
    const float* W2r        = (const float*)d_in[8];
    const float* Wlin       = (const float*)d_in[9];
    const float* blin       = (const float*)d_in[10];
    float* out = (float*)d_out;

    const int N = in_sizes[0] / 128;       // 50000
    const int E = in_sizes[1] / 2;         // 800000
    const int P = in_sizes[2] / 2;         // 200000

    const int* src = edge_index;
    const int* dst = edge_index + E;
    const int* ps  = edge_pairs;
    const int* pd  = edge_pairs + P;

    // workspace layout (16B-aligned chunks)
    ushort16* xh    = (ushort16*)d_ws;                 // N*128 bf16
    ushort16* meanh = xh + (size_t)N * 128;            // N*128 bf16
    ushort16* h     = meanh + (size_t)N * 128;         // N*128 bf16
    ushort16* W1t   = h + (size_t)N * 128;             // 128*256 bf16
    float* fw     = (float*)(W1t + 128 * 256);         // 512 f32 (va|vc|vbp|vd)
    float* fc     = fw + 512;                          // 2 f32 (+2 pad)
    float2* pab   = (float2*)(fc + 4);                 // N float2 (pa,pc)
    float2* quv   = pab + N;                           // N float2 (qb,qd)
    float* za     = (float*)(quv + N);                 // N f32
    float* zb     = za + N;                            // N f32
    int* deg      = (int*)(zb + N);
    int* rowptr   = deg + N;
    int* cursor   = rowptr + N + 1;
    ushort16* esrc = (ushort16*)(cursor + N);          // E ushort
    int* partials = (int*)(esrc + E);

    const int scan_blocks = (N + 255) / 256;           // 196
    const long long n4 = (long long)N * 128 / 4;       // 1.6M
    const int nbx  = (int)((n4 + 255) / 256);          // 6250
    const int nbw1 = 128;
    const int nbh  = ((E + 3) / 4 + 255) / 256;        // 782
    const int histT = nbh * 256;                       // 200192

    hipMemsetAsync(deg, 0, (size_t)N * sizeof(int), stream);

    // fused prep: cast x, cast+transpose W1, fold W2/Wlin/b2, degree histogram
    prep_kernel<<<nbx + nbw1 + 1 + nbh, 256, 0, stream>>>(
        x, (uint32*)xh, n4, W1l, W1r, W1t, W2l, W2r, Wlin, b2, fw, fc,
        dst, deg, E, nbx, nbw1, histT);

    // CSR scan + fill
    partial_sum_kernel<<<scan_blocks, 256, 0, stream>>>(deg, partials, N);
    scan_partials_kernel<<<1, 256, 0, stream>>>(partials, scan_blocks);
    scan_final_kernel<<<scan_blocks, 256, 0, stream>>>(deg, partials, rowptr, cursor, N);
    fill_kernel<<<nbh, 256, 0, stream>>>(src, dst, cursor, esrc, E, histT);

    // layer 1
    agg_mean_x_kernel<<<(N + 3) / 4, 256, 0, stream>>>((const uint32*)xh, rowptr, esrc,
                                                       (uint32*)meanh, N);
    gemm1_mfma_kernel<<<(N + 63) / 64, 256, 0, stream>>>(meanh, xh, W1t, b1, h, N);

    // folded layer 2: 4 dots per node, then scalar aggregation
    gemv_kernel<<<(N + 3) / 4, 256, 0, stream>>>((const uint32*)h, fw, pab, quv, N);
    agg_link_kernel<<<(N + 255) / 256, 256, 0, stream>>>(pab, quv, rowptr, esrc, fc,
                                                         za, zb, N);

    // link prediction
    link_kernel<<<(P + 255) / 256, 256, 0, stream>>>(za, zb, ps, pd, blin, out, P);
}